// Round 7
// baseline (413.034 us; speedup 1.0000x reference)
//
#include <hip/hip_runtime.h>
#include <hip/hip_bf16.h>
#include <type_traits>

// GNN: GAT(128->4x32) -> GAT(128->4x32) -> GraphConv(128->32) -> SAGE(32->32)
//      -> global mean pool (64 graphs) -> MLP(32->32->10)
// R7: bucketed CSR build (counting sort by dst>>8).         361 us
// R8: branchless gat_aggr; attention fused into GEMM.       359
// R9/R11: 4-deep gather pipeline, grid-stride GEMMs.        356
// R12: multi-dst-per-wave aggr.                             328.9
// R13: gat 4 dst/wave no-reduce, 32ch 8/wave.               327.9 (null ->
//     gathers at memory-system floor; ~205MB L3 traffic/dispatch ~ 21us min)
// R14: sage_fused (mean+gemm+pool), 8-deep gat gather.      311.4
// R15: dispatch elimination. bucket_hist: atomic-free per-block hist dump
//     + absorbs weight-prep + zeroes gpool/dcounter (kills 2 memsets);
//     scan-only stub; head fused into sage_fused via last-block ticket
//     (device-scope atomics + threadfence, LDS union). 14 -> 11 dispatches.

typedef __bf16 v8bf __attribute__((ext_vector_type(8)));
typedef float  v4f  __attribute__((ext_vector_type(4)));

__device__ __forceinline__ float lrelu(float x) { return x > 0.f ? x : 0.2f * x; }

__device__ __forceinline__ unsigned short f2bf(float f) {
    unsigned u = __float_as_uint(f);
    unsigned r = (u + 0x7FFF + ((u >> 16) & 1)) >> 16;   // RNE
    return (unsigned short)r;
}
__device__ __forceinline__ float bfbits2f(unsigned short u) {
    return __uint_as_float((unsigned)u << 16);
}
__device__ __forceinline__ float bflo(int v) { return __uint_as_float((unsigned)v << 16); }
__device__ __forceinline__ float bfhi(int v) { return __uint_as_float((unsigned)v & 0xffff0000u); }
__device__ __forceinline__ int packbf2(float a, float b) {
    return (int)f2bf(a) | ((int)f2bf(b) << 16);
}

__device__ __forceinline__ void fma8(float* acc, int4 u, float w) {
    acc[0] += w * bflo(u.x); acc[1] += w * bfhi(u.x);
    acc[2] += w * bflo(u.y); acc[3] += w * bfhi(u.y);
    acc[4] += w * bflo(u.z); acc[5] += w * bfhi(u.z);
    acc[6] += w * bflo(u.w); acc[7] += w * bfhi(u.w);
}

// ================= bucketed CSR build =================
// bucket = dst >> 8 (256 dst per bucket); pairs word = (dst&255)<<17 | src.

// Per-block histogram dump (no global atomics) + weight prep (blocks 1..64)
// + gpool/dcounter zeroing (block 0). Weight prep is dependency-free work
// hidden under the histogram pass.
__global__ __launch_bounds__(256) void bucket_hist(
    const int* __restrict__ dst, int* __restrict__ histg, int E, int nbuck,
    float* __restrict__ gpool, int* __restrict__ dcounter,
    const float* __restrict__ W1, const float* __restrict__ W2,
    const float* __restrict__ W3r, const float* __restrict__ W3l,
    const float* __restrict__ as1, const float* __restrict__ ad1,
    const float* __restrict__ as2, const float* __restrict__ ad2,
    __hip_bfloat16* __restrict__ W1t, __hip_bfloat16* __restrict__ W2t,
    __hip_bfloat16* __restrict__ W3rt, __hip_bfloat16* __restrict__ W3lt)
{
    __shared__ int hist[256];
    int t = threadIdx.x;
    hist[t] = 0;
    __syncthreads();
    int base = blockIdx.x * 4096;
    #pragma unroll
    for (int k = 0; k < 16; ++k) {
        int e = base + k * 256 + t;
        if (e < E) atomicAdd(&hist[dst[e] >> 8], 1);
    }
    __syncthreads();
    histg[blockIdx.x * 256 + t] = hist[t];

    if (blockIdx.x == 0) {                  // zero pool accumulators + ticket
        for (int i = t; i < 64 * 32; i += 256) gpool[i] = 0.f;
        if (t == 0) *dcounter = 0;
    }
    if (blockIdx.x >= 1 && blockIdx.x <= 64) {
        int b = blockIdx.x - 1;             // 0..63
        int i = b * 256 + t;                // 0..16383
        {   // transpose W1/W2 into rows 0..127 of the 144-row layout
            int k = i >> 7, c = i & 127;
            *(unsigned short*)&W1t[c * 128 + k] = f2bf(W1[i]);
            *(unsigned short*)&W2t[c * 128 + k] = f2bf(W2[i]);
        }
        if (i < 4096) {
            int k = i >> 5, c = i & 31;
            *(unsigned short*)&W3rt[c * 128 + k] = f2bf(W3r[i]);
            *(unsigned short*)&W3lt[c * 128 + k] = f2bf(W3l[i]);
        }
        if (b == 0) {                       // attention-dot columns: 512 units
            for (int u = t; u < 512; u += 256) {
                int k = u & 127, hd = u >> 7;
                float vs1 = 0.f, vd1 = 0.f, vs2 = 0.f, vd2 = 0.f;
                #pragma unroll
                for (int j = 0; j < 32; ++j) {
                    int c = hd * 32 + j;
                    float w1 = W1[k * 128 + c], w2 = W2[k * 128 + c];
                    vs1 += w1 * as1[c]; vd1 += w1 * ad1[c];
                    vs2 += w2 * as2[c]; vd2 += w2 * ad2[c];
                }
                unsigned short h1s = f2bf(vs1), h1d = f2bf(vd1);
                unsigned short h2s = f2bf(vs2), h2d = f2bf(vd2);
                *(unsigned short*)&W1t[(128 + hd) * 128 + k] = h1s;
                *(unsigned short*)&W1t[(132 + hd) * 128 + k] = f2bf(vs1 - bfbits2f(h1s));
                *(unsigned short*)&W1t[(136 + hd) * 128 + k] = h1d;
                *(unsigned short*)&W1t[(140 + hd) * 128 + k] = f2bf(vd1 - bfbits2f(h1d));
                *(unsigned short*)&W2t[(128 + hd) * 128 + k] = h2s;
                *(unsigned short*)&W2t[(132 + hd) * 128 + k] = f2bf(vs2 - bfbits2f(h2s));
                *(unsigned short*)&W2t[(136 + hd) * 128 + k] = h2d;
                *(unsigned short*)&W2t[(140 + hd) * 128 + k] = f2bf(vd2 - bfbits2f(h2d));
            }
        }
    }
}

// 1-block scan over summed per-block histograms.
__global__ __launch_bounds__(256) void scan_kernel(
    const int* __restrict__ histg, int nblkh,
    int* __restrict__ bbase, int* __restrict__ gcursor,
    int nbuck, int E, int* __restrict__ rowptr, int n)
{
    __shared__ int red[256];
    int t = threadIdx.x;
    int v = 0;
    for (int b = 0; b < nblkh; ++b) v += histg[b * 256 + t];
    if (t >= nbuck) v = 0;
    red[t] = v;
    __syncthreads();
    for (int off = 1; off < 256; off <<= 1) {
        int u = (t >= off) ? red[t - off] : 0;
        __syncthreads();
        red[t] += u;
        __syncthreads();
    }
    int ex = red[t] - v;
    if (t < nbuck) { bbase[t] = ex; gcursor[t] = ex; }
    if (t == 0) { bbase[nbuck] = E; rowptr[n] = E; }
}

__global__ __launch_bounds__(256) void bucket_scatter(const int* __restrict__ dst,
                                                      const int* __restrict__ src,
                                                      int* __restrict__ gcursor,
                                                      int* __restrict__ pairs,
                                                      int E, int nbuck) {
    __shared__ int hist[256], lcur[256];
    int t = threadIdx.x;
    for (int i = t; i < nbuck; i += 256) hist[i] = 0;
    __syncthreads();
    int base = blockIdx.x * 2048;
    int dreg[8];
    #pragma unroll
    for (int k = 0; k < 8; ++k) {
        int e = base + k * 256 + t;
        int d = (e < E) ? dst[e] : -1;
        dreg[k] = d;
        if (d >= 0) atomicAdd(&hist[d >> 8], 1);
    }
    __syncthreads();
    for (int i = t; i < nbuck; i += 256) {
        int c = hist[i];
        lcur[i] = c ? atomicAdd(&gcursor[i], c) : 0;   // reserve contiguous run
    }
    __syncthreads();
    #pragma unroll
    for (int k = 0; k < 8; ++k) {
        int e = base + k * 256 + t;
        if (e < E) {
            int d = dreg[k];
            int p = atomicAdd(&lcur[d >> 8], 1);
            pairs[p] = ((d & 255) << 17) | src[e];
        }
    }
}

__global__ __launch_bounds__(256) void bucket_fill(const int* __restrict__ pairs,
                                                   const int* __restrict__ bbase,
                                                   int* __restrict__ rowptr,
                                                   int* __restrict__ colsrc, int n) {
    __shared__ int deg[256], excl[256], cur[256];
    int b = blockIdx.x, t = threadIdx.x;
    int e0 = bbase[b], e1 = bbase[b + 1];
    int d0 = b << 8;
    deg[t] = 0;
    __syncthreads();
    for (int j = e0 + t; j < e1; j += 256)
        atomicAdd(&deg[pairs[j] >> 17], 1);
    __syncthreads();
    int v = deg[t];
    excl[t] = v;
    __syncthreads();
    for (int off = 1; off < 256; off <<= 1) {
        int u = (t >= off) ? excl[t - off] : 0;
        __syncthreads();
        excl[t] += u;
        __syncthreads();
    }
    int base = e0 + excl[t] - v;                   // exclusive
    if (d0 + t < n) rowptr[d0 + t] = base;
    cur[t] = base;
    __syncthreads();
    for (int j = e0 + t; j < e1; j += 256) {
        int w = pairs[j];
        int p = atomicAdd(&cur[w >> 17], 1);
        colsrc[p] = w & 0x1FFFF;
    }
}

// ---------------- GAT GEMM via MFMA: [h | a_s | a_d] = X @ Wt(144 cols) ----------
// Grid-stride over 16-row tiles; weights staged in LDS once per block.
template <typename T>
__global__ __launch_bounds__(256) void gemm_att_mfma(
    const T* __restrict__ X, const __hip_bfloat16* __restrict__ Wt,
    __hip_bfloat16* __restrict__ h, float* __restrict__ a_s, float* __restrict__ a_d, int n)
{
    __shared__ __align__(16) __hip_bfloat16 sWt[144 * 136];   // [col][k], +8 pad
    int t = threadIdx.x;
    for (int i = t; i < 144 * 16; i += 256) {
        int row = i >> 4, chh = i & 15;
        *(int4*)&sWt[row * 136 + chh * 8] = *(const int4*)&Wt[row * 128 + chh * 8];
    }
    __syncthreads();
    int wave = t >> 6, lane = t & 63, quad = lane >> 4, l16 = lane & 15;

    v8bf z;
    #pragma unroll
    for (int i = 0; i < 8; ++i) z[i] = (__bf16)0.f;

    int nrb = (n + 15) >> 4;
    for (int rb = blockIdx.x * 4 + wave; rb < nrb; rb += gridDim.x * 4) {
        int rowbase = rb * 16;
        int arow = rowbase + l16;
        bool ok = arow < n;
        v8bf af[4];
        if constexpr (std::is_same<T, float>::value) {
            const float* xf = X + (size_t)(ok ? arow : 0) * 128;
            #pragma unroll
            for (int ks = 0; ks < 4; ++ks) {
                if (ok) {
                    float4 u = *(const float4*)&xf[ks * 32 + quad * 8];
                    float4 v = *(const float4*)&xf[ks * 32 + quad * 8 + 4];
                    v8bf a;
                    unsigned short r;
                    r = f2bf(u.x); a[0] = *(__bf16*)&r;
                    r = f2bf(u.y); a[1] = *(__bf16*)&r;
                    r = f2bf(u.z); a[2] = *(__bf16*)&r;
                    r = f2bf(u.w); a[3] = *(__bf16*)&r;
                    r = f2bf(v.x); a[4] = *(__bf16*)&r;
                    r = f2bf(v.y); a[5] = *(__bf16*)&r;
                    r = f2bf(v.z); a[6] = *(__bf16*)&r;
                    r = f2bf(v.w); a[7] = *(__bf16*)&r;
                    af[ks] = a;
                } else af[ks] = z;
            }
        } else {
            const v8bf* px = (const v8bf*)(X + (size_t)(ok ? arow : 0) * 128);
            #pragma unroll
            for (int ks = 0; ks < 4; ++ks) af[ks] = ok ? px[ks * 4 + quad] : z;
        }

        v4f acc[9];
        #pragma unroll
        for (int ct = 0; ct < 9; ++ct) acc[ct] = (v4f){0.f, 0.f, 0.f, 0.f};
        #pragma unroll
        for (int ct = 0; ct < 9; ++ct) {
            #pragma unroll
            for (int ks = 0; ks < 4; ++ks) {
                v8bf b = *(const v8bf*)&sWt[(ct * 16 + l16) * 136 + ks * 32 + quad * 8];
                acc[ct] = __builtin_amdgcn_mfma_f32_16x16x32_bf16(af[ks], b, acc[ct], 0, 0, 0);
            }
        }

        // h store (tiles 0..7): C layout col=l16, row=quad*4+reg
        #pragma unroll
        for (int reg = 0; reg < 4; ++reg) {
            int r = rowbase + quad * 4 + reg;
            if (r < n) {
                #pragma unroll
                for (int ct = 0; ct < 8; ++ct)
                    *(unsigned short*)&h[(size_t)r * 128 + ct * 16 + l16] = f2bf(acc[ct][reg]);
            }
        }
        // tile 8 = attention dots: cols l16: 0-3 s_hi, 4-7 s_lo, 8-11 d_hi, 12-15 d_lo
        #pragma unroll
        for (int reg = 0; reg < 4; ++reg) {
            float v = acc[8][reg] + __shfl_xor(acc[8][reg], 4);   // hi + lo
            int r = rowbase + quad * 4 + reg;
            if (r < n) {
                if (l16 < 4)                    a_s[r * 4 + l16] = v;
                else if (l16 >= 8 && l16 < 12)  a_d[r * 4 + (l16 - 8)] = v;
            }
        }
    }
}

// ---------------- GAT: 4 dst per wave (16 lanes each), 8-deep gather -------------
__global__ __launch_bounds__(256) void gat_aggr(
    const __hip_bfloat16* __restrict__ h, const float* __restrict__ a_s,
    const float* __restrict__ a_d,
    const int* __restrict__ rowptr, const int* __restrict__ colsrc,
    const float* __restrict__ bias, __hip_bfloat16* __restrict__ out, int n)
{
    __shared__ float s_w[4][4 * 16 * 4];           // [wave][q*64 + j*4 + head]
    int t = threadIdx.x;
    int wave = t >> 6, lane = t & 63;
    int q = lane >> 4, l16 = lane & 15;            // quarter = dst slot
    int d = blockIdx.x * 16 + wave * 4 + q;
    if (d >= n) d = n - 1;                         // duplicate work, benign
    int beg = rowptr[d];
    int cnt = rowptr[d + 1] - beg;
    int cm = max(cnt, __shfl_xor(cnt, 16));
    cm = max(cm, __shfl_xor(cm, 32));              // wave-uniform trip bound
    float4 ad4 = *(const float4*)&a_d[d * 4];
    float4 asd = *(const float4*)&a_s[d * 4];

    int ch = l16 * 8;                              // channels ch..ch+7
    int head = l16 >> 2;
    const char* hb = (const char*)h;
    unsigned chb = (unsigned)(ch << 1);            // byte offset within row
    int sbase = q * 64;                            // s_w base (floats)
    int lbase = q * 16;                            // shfl lane base

    float acc[8];
    #pragma unroll
    for (int i = 0; i < 8; ++i) acc[i] = 0.f;
    float zp = 0.f;                                // complete z for own head

    for (int j0 = 0; j0 < cm; j0 += 16) {
        int ne = cnt - j0;                         // own-dst remaining (may be <=0)
        float w0 = 0.f, w1 = 0.f, w2 = 0.f, w3 = 0.f;
        int s = 0;                                 // row 0 is a valid address
        if (l16 < ne) {
            s = colsrc[beg + j0 + l16];
            float4 sv = *(const float4*)&a_s[s * 4];
            w0 = __expf(lrelu(sv.x + ad4.x));
            w1 = __expf(lrelu(sv.y + ad4.y));
            w2 = __expf(lrelu(sv.z + ad4.z));
            w3 = __expf(lrelu(sv.w + ad4.w));
        }
        float4 wv = {w0, w1, w2, w3};              // zeros for pad lanes
        *(float4*)&s_w[wave][sbase + l16 * 4] = wv;
        __asm volatile("s_waitcnt lgkmcnt(0)" ::: "memory");  // wave-sync LDS
        // BRANCHLESS: s_w[j]==0 and s==0 for pad lanes / exhausted dsts.
        int nemax = cm - j0; if (nemax > 16) nemax = 16;
        int k = 0;
        for (; k + 8 <= nemax; k += 8) {           // 8 loads in flight per dst
            int   ss[8];
            float wj[8];
            int4  u[8];
            #pragma unroll
            for (int p2 = 0; p2 < 8; ++p2) {
                ss[p2] = __shfl(s, lbase + k + p2);
                wj[p2] = s_w[wave][sbase + (k + p2) * 4 + head];
            }
            #pragma unroll
            for (int p2 = 0; p2 < 8; ++p2)
                u[p2] = *(const int4*)(hb + (((unsigned)ss[p2] << 8) + chb));
            #pragma unroll
            for (int p2 = 0; p2 < 8; ++p2) { zp += wj[p2]; fma8(acc, u[p2], wj[p2]); }
        }
        for (; k + 4 <= nemax; k += 4) {           // 4-deep tail
            int ss0 = __shfl(s, lbase + k);
            int ss1 = __shfl(s, lbase + k + 1);
            int ss2 = __shfl(s, lbase + k + 2);
            int ss3 = __shfl(s, lbase + k + 3);
            float wj0 = s_w[wave][sbase + k * 4 + head];
            float wj1 = s_w[wave][sbase + (k + 1) * 4 + head];
            float wj2 = s_w[wave][sbase + (k + 2) * 4 + head];
            float wj3 = s_w[wave][sbase + (k + 3) * 4 + head];
            int4 u0 = *(const int4*)(hb + (((unsigned)ss0 << 8) + chb));
            int4 u1 = *(const int4*)(hb + (((unsigned)ss1 << 8) + chb));
            int4 u2 = *(const int4*)(hb + (((unsigned)ss2 << 8) + chb));
            int4 u3 = *(const int4*)(hb + (((unsigned)ss3 << 8) + chb));
            zp += (wj0 + wj1) + (wj2 + wj3);
            fma8(acc, u0, wj0);
            fma8(acc, u1, wj1);
            fma8(acc, u2, wj2);
            fma8(acc, u3, wj3);
        }
        for (; k < nemax; ++k) {                   // <=3 singles
            int ss0 = __shfl(s, lbase + k);
            float wj0 = s_w[wave][sbase + k * 4 + head];
            int4 u0 = *(const int4*)(hb + (((unsigned)ss0 << 8) + chb));
            zp += wj0;
            fma8(acc, u0, wj0);
        }
    }

    // epilogue: every lane writes 16B (16 lanes cover the 128-ch row)
    int4 hu = *(const int4*)(hb + (((unsigned)d << 8) + chb));
    float4 b0 = *(const float4*)&bias[ch];
    float4 b1 = *(const float4*)&bias[ch + 4];
    float eh0 = lrelu(asd.x + ad4.x), eh1 = lrelu(asd.y + ad4.y);
    float eh2 = lrelu(asd.z + ad4.z), eh3 = lrelu(asd.w + ad4.w);
    float eh = (head < 2) ? (head == 0 ? eh0 : eh1) : (head == 2 ? eh2 : eh3);
    float ws = __expf(eh);                         // self-loop weight
    float inv = 1.f / (zp + ws + 1e-16f);
    float hs[8] = {bflo(hu.x), bfhi(hu.x), bflo(hu.y), bfhi(hu.y),
                   bflo(hu.z), bfhi(hu.z), bflo(hu.w), bfhi(hu.w)};
    float o[8];
    o[0] = fmaxf((acc[0] + ws * hs[0]) * inv + b0.x, 0.f);
    o[1] = fmaxf((acc[1] + ws * hs[1]) * inv + b0.y, 0.f);
    o[2] = fmaxf((acc[2] + ws * hs[2]) * inv + b0.z, 0.f);
    o[3] = fmaxf((acc[3] + ws * hs[3]) * inv + b0.w, 0.f);
    o[4] = fmaxf((acc[4] + ws * hs[4]) * inv + b1.x, 0.f);
    o[5] = fmaxf((acc[5] + ws * hs[5]) * inv + b1.y, 0.f);
    o[6] = fmaxf((acc[6] + ws * hs[6]) * inv + b1.z, 0.f);
    o[7] = fmaxf((acc[7] + ws * hs[7]) * inv + b1.w, 0.f);
    int4 ou;
    ou.x = packbf2(o[0], o[1]); ou.y = packbf2(o[2], o[3]);
    ou.z = packbf2(o[4], o[5]); ou.w = packbf2(o[6], o[7]);
    *(int4*)&out[(size_t)d * 128 + ch] = ou;
}

// ---------------- GraphConv linear: y = x@Wr (bf16), root = x@Wl + b (fp32) -------
__global__ __launch_bounds__(256) void graphconv_lin(
    const __hip_bfloat16* __restrict__ Xb,
    const __hip_bfloat16* __restrict__ Wrt, const __hip_bfloat16* __restrict__ Wlt,
    const float* __restrict__ bias, __hip_bfloat16* __restrict__ y,
    float* __restrict__ root, int n)
{
    __shared__ __align__(16) __hip_bfloat16 sWr[32 * 136], sWl[32 * 136];
    int t = threadIdx.x;
    for (int i = t; i < 32 * 16; i += 256) {
        int row = i >> 4, chh = i & 15;
        *(int4*)&sWr[row * 136 + chh * 8] = *(const int4*)&Wrt[row * 128 + chh * 8];
        *(int4*)&sWl[row * 136 + chh * 8] = *(const int4*)&Wlt[row * 128 + chh * 8];
    }
    __syncthreads();
    int wave = t >> 6, lane = t & 63, quad = lane >> 4, l16 = lane & 15;

    v8bf z;
    #pragma unroll
    for (int i = 0; i < 8; ++i) z[i] = (__bf16)0.f;

    int nrb = (n + 15) >> 4;
    for (int rb = blockIdx.x * 4 + wave; rb < nrb; rb += gridDim.x * 4) {
        int rowbase = rb * 16;
        int arow = rowbase + l16;
        bool ok = arow < n;
        const v8bf* px = (const v8bf*)(Xb + (size_t)(ok ? arow : 0) * 128);
        v8bf fx[4];
        #pragma unroll
        for (int ks = 0; ks < 4; ++ks) fx[ks] = ok ? px[ks * 4 + quad] : z;

        v4f accR[2], accL[2];
        #pragma unroll
        for (int ct = 0; ct < 2; ++ct) {
            accR[ct] = (v4f){0.f, 0.f, 0.f, 0.f};
            accL[ct] = (v4f){0.f, 0.f, 0.f, 0.f};
            #pragma unroll
            for (int ks = 0; ks < 4; ++ks) {
                v8bf br = *(const v8bf*)&sWr[(ct * 16 + l16) * 136 + ks * 32 + quad * 8];
                accR[ct] = __builtin_amdgcn_mfma_f32_16x16x32_bf16(fx[ks], br, accR[ct], 0, 0, 0);
                v8bf bl = *(const v8bf*)&sWl[(ct * 16 + l16) * 136 + ks * 32 + quad * 8];
                accL[ct] = __builtin_amdgcn_mfma_f32_16x16x32_bf16(fx[ks], bl, accL[ct], 0, 0, 0);
            }
        }
        #pragma unroll
        for (int ct = 0; ct < 2; ++ct) {
            float bcol = bias[ct * 16 + l16];
            #pragma unroll
            for (int reg = 0; reg < 4; ++reg) {
                int r = rowbase + quad * 4 + reg;
                if (r < n) {
                    *(unsigned short*)&y[(size_t)r * 32 + ct * 16 + l16] = f2bf(accR[ct][reg]);
                    root[(size_t)r * 32 + ct * 16 + l16] = accL[ct][reg] + bcol;
                }
            }
        }
    }
}

// ---------------- GraphConv aggr: 8 dst per wave (8 lanes each), 32 ch -----------
__global__ __launch_bounds__(256) void graphconv_aggr(
    const __hip_bfloat16* __restrict__ y, const float* __restrict__ root,
    const int* __restrict__ rowptr, const int* __restrict__ colsrc,
    __hip_bfloat16* __restrict__ x3, int n)
{
    int t = threadIdx.x;
    int wave = t >> 6, lane = t & 63;
    int oct = lane >> 3, ol = lane & 7;            // octet = dst slot
    int d = blockIdx.x * 32 + wave * 8 + oct;
    if (d >= n) d = n - 1;
    int beg = rowptr[d];
    int cnt = rowptr[d + 1] - beg;
    int cm = max(cnt, __shfl_xor(cnt, 8));
    cm = max(cm, __shfl_xor(cm, 16));
    cm = max(cm, __shfl_xor(cm, 32));              // wave-uniform trip bound
    int l4 = ol & 3, egrp = ol >> 2;               // 2 edge-groups x 4 ch-lanes
    int ch = l4 * 8;
    int lbase = oct * 8;
    float acc[8];
    #pragma unroll
    for (int i = 0; i < 8; ++i) acc[i] = 0.f;
    for (int j0 = 0; j0 < cm; j0 += 8) {
        int ne = cnt - j0;                         // own-dst remaining
        int s = (ol < ne) ? colsrc[beg + j0 + ol] : 0;
        int nemax = cm - j0; if (nemax > 8) nemax = 8;
        int kmax = (nemax + 1) >> 1;               // uniform trip count
        int k = 0;
        for (; k + 2 <= kmax; k += 2) {            // 4 edges in flight
            int ja = egrp + 2 * k, jb = ja + 2;
            int sa = __shfl(s, lbase + ja);
            int sb = __shfl(s, lbase + jb);
            float ma = (ja < ne) ? 1.f : 0.f;      // branchless mask (own dst)
            float mb = (jb < ne) ? 1.f : 0.f;
            int4 ua = *(const int4*)&y[(size_t)sa * 32 + ch];
            int4 ub = *(const int4*)&y[(size_t)sb * 32 + ch];
            fma8(acc, ua, ma);
            fma8(acc, ub, mb);
        }
        if (k < kmax) {
            int ja = egrp + 2 * k;
            int sa = __shfl(s, lbase + ja);
            float ma = (ja < ne) ? 1.f : 0.f;
            int4 ua = *(const int4*)&y[(size_t)sa * 32 + ch];
            fma8(acc, ua, ma);
        }
    }
    float4 r0 = {0.f, 0.f, 0.f, 0.f}, r1 = {0.f, 0.f, 0.f, 0.f};
    if (egrp == 0) {                               // hoist above reduction
        r0 = *(const float4*)&root[(size_t)d * 32 + ch];
        r1 = *(const float4*)&root[(size_t)d * 32 + ch + 4];
    }
    #pragma unroll
    for (int i = 0; i < 8; ++i) acc[i] += __shfl_xor(acc[i], 4);   // combine 2 groups
    if (egrp == 0) {                               // 4 lanes per dst write 16B each
        float o[8];
        o[0] = fmaxf(acc[0] + r0.x, 0.f); o[1] = fmaxf(acc[1] + r0.y, 0.f);
        o[2] = fmaxf(acc[2] + r0.z, 0.f); o[3] = fmaxf(acc[3] + r0.w, 0.f);
        o[4] = fmaxf(acc[4] + r1.x, 0.f); o[5] = fmaxf(acc[5] + r1.y, 0.f);
        o[6] = fmaxf(acc[6] + r1.z, 0.f); o[7] = fmaxf(acc[7] + r1.w, 0.f);
        int4 ou;
        ou.x = packbf2(o[0], o[1]); ou.y = packbf2(o[2], o[3]);
        ou.z = packbf2(o[4], o[5]); ou.w = packbf2(o[6], o[7]);
        *(int4*)&x3[(size_t)d * 32 + ch] = ou;
    }
}

// ---------------- SAGE fused: mean-gather + 32x32 GEMM + pool + MLP head ---------
// Block = 32 dsts. Per-graph pool partials -> LDS -> global atomics; the LAST
// block (device-scope ticket) additionally runs the MLP head. LDS is a union
// (phase A: weights/mean/x/acc; phase B: head buffers) to keep 25KB/block.
__device__ __forceinline__ int lower_bound_i(const int* a, int n, int key) {
    int lo = 0, hi = n;
    while (lo < hi) { int mid = (lo + hi) >> 1; if (a[mid] < key) lo = mid + 1; else hi = mid; }
    return lo;
}

__global__ __launch_bounds__(256) void sage_fused(
    const __hip_bfloat16* __restrict__ x3, const int* __restrict__ rowptr,
    const int* __restrict__ colsrc,
    const float* __restrict__ Wl, const float* __restrict__ bl,
    const float* __restrict__ Wr,
    const int* __restrict__ batch, float* __restrict__ gpool, int n,
    const float* __restrict__ Wf1, const float* __restrict__ bf1,
    const float* __restrict__ Wf2, const float* __restrict__ bf2,
    float* __restrict__ out, int* __restrict__ dcounter)
{
    __shared__ __align__(16) float lds[6144];      // 24KB union
    __shared__ int sbat[32];
    __shared__ int slast;
    float* sWl   = lds;                            // [1024]
    float* sWr   = lds + 1024;                     // [1024]
    float* smean = lds + 2048;                     // [1024]
    float* sx    = lds + 3072;                     // [1024]
    float* sacc  = lds + 4096;                     // [2048]
    int t = threadIdx.x;
    int row0 = blockIdx.x * 32;
    for (int i = t; i < 1024; i += 256) {
        sWl[i] = Wl[i]; sWr[i] = Wr[i];
    }
    for (int i = t; i < 2048; i += 256) sacc[i] = 0.f;
    if (t < 32) sbat[t] = batch[min(row0 + t, n - 1)];

    // ---- gather phase: 8 dst per wave, mean into LDS ----
    int wave = t >> 6, lane = t & 63;
    int oct = lane >> 3, ol = lane & 7;
    int slot = wave * 8 + oct;                     // 0..31
    int d = row0 + slot;
    if (d >= n) d = n - 1;
    int beg = rowptr[d];
    int cnt = rowptr[d + 1] - beg;
    int cm = max(cnt, __shfl_xor(cnt, 8));
    cm = max(cm, __shfl_xor(cm, 16));
    cm = max(cm, __shfl_xor(cm, 32));
    int l4 = ol & 3, egrp = ol >> 2;
    int ch = l4 * 8;
    int lbase = oct * 8;
    float acc[8];
    #pragma unroll
    for (int i = 0; i < 8; ++i) acc[i] = 0.f;
    for (int j0 = 0; j0 < cm; j0 += 8) {
        int ne = cnt - j0;
        int s = (ol < ne) ? colsrc[beg + j0 + ol] : 0;
        int nemax = cm - j0; if (nemax > 8) nemax = 8;
        int kmax = (nemax + 1) >> 1;
        int k = 0;
        for (; k + 2 <= kmax; k += 2) {
            int ja = egrp + 2 * k, jb = ja + 2;
            int sa = __shfl(s, lbase + ja);
            int sb = __shfl(s, lbase + jb);
            float ma = (ja < ne) ? 1.f : 0.f;
            float mb = (jb < ne) ? 1.f : 0.f;
            int4 ua = *(const int4*)&x3[(size_t)sa * 32 + ch];
            int4 ub = *(const int4*)&x3[(size_t)sb * 32 + ch];
            fma8(acc, ua, ma);
            fma8(acc, ub, mb);
        }
        if (k < kmax) {
            int ja = egrp + 2 * k;
            int sa = __shfl(s, lbase + ja);
            float ma = (ja < ne) ? 1.f : 0.f;
            int4 ua = *(const int4*)&x3[(size_t)sa * 32 + ch];
            fma8(acc, ua, ma);
        }
    }
    #pragma unroll
    for (int i = 0; i < 8; ++i) acc[i] += __shfl_xor(acc[i], 4);
    if (egrp == 0) {                               // stage mean + own x3 row
        float invd = 1.f / fmaxf((float)cnt, 1.f);
        float4 lo = {acc[0] * invd, acc[1] * invd, acc[2] * invd, acc[3] * invd};
        float4 hi = {acc[4] * invd, acc[5] * invd, acc[6] * invd, acc[7] * invd};
        *(float4*)&smean[slot * 32 + ch]     = lo;
        *(float4*)&smean[slot * 32 + ch + 4] = hi;
        int4 xu = *(const int4*)&x3[(size_t)d * 32 + ch];
        float4 x0 = {bflo(xu.x), bfhi(xu.x), bflo(xu.y), bfhi(xu.y)};
        float4 x1 = {bflo(xu.z), bfhi(xu.z), bflo(xu.w), bfhi(xu.w)};
        *(float4*)&sx[slot * 32 + ch]     = x0;
        *(float4*)&sx[slot * 32 + ch + 4] = x1;
    }
    __syncthreads();

    // ---- GEMM + pool-accumulate ----
    int c = t & 31, rr = t >> 5;
    float bc = bl[c];
    int gbase = sbat[0];
    #pragma unroll
    for (int kr = 0; kr < 4; ++kr) {
        int r = rr + 8 * kr;
        float a = bc;
        const float4* pm = (const float4*)&smean[r * 32];
        const float4* px = (const float4*)&sx[r * 32];
        #pragma unroll
        for (int k4 = 0; k4 < 8; ++k4) {
            float4 vm = pm[k4], vx = px[k4];
            const float* wl = &sWl[(k4 * 4) * 32 + c];
            const float* wr = &sWr[(k4 * 4) * 32 + c];
            a += vm.x * wl[0] + vm.y * wl[32] + vm.z * wl[64] + vm.w * wl[96];
            a += vx.x * wr[0] + vx.y * wr[32] + vx.z * wr[64] + vx.w * wr[96];
        }
        float v = fmaxf(a, 0.f);
        int row = row0 + r;
        if (row < n) atomicAdd(&sacc[(sbat[r] - gbase) * 32 + c], v);
    }
    __syncthreads();
    int ngr = sbat[31] - gbase + 1;                // graphs spanned by this block
    for (int i = t; i < ngr * 32; i += 256) {
        float v = sacc[i];
        if (v != 0.f) atomicAdd(&gpool[(size_t)gbase * 32 + i], v);
    }

    // ---- last-block ticket -> MLP head ----
    __threadfence();
    if (t == 0) slast = (atomicAdd(dcounter, 1) == (int)gridDim.x - 1) ? 1 : 0;
    __syncthreads();
    if (!slast) return;
    __threadfence();
    float* sg   = lds;                             // [2048]  (union reuse)
    float* st   = lds + 2048;                      // [2048]
    float* sW1  = lds + 4096;                      // [1024]
    float* sW2  = lds + 5120;                      // [320]
    float* sinv = lds + 5440;                      // [64]
    if (t < 64) {
        int lo = lower_bound_i(batch, n, t);
        int hi = lower_bound_i(batch, n, t + 1);
        sinv[t] = 1.f / fmaxf((float)(hi - lo), 1.f);
    }
    for (int i = t; i < 1024; i += 256) sW1[i] = Wf1[i];
    for (int i = t; i < 320; i += 256) sW2[i] = Wf2[i];
    __syncthreads();
    // atomic read-back: guarantees device-coherent view of other XCDs' adds
    for (int i = t; i < 2048; i += 256) sg[i] = atomicAdd(&gpool[i], 0.f) * sinv[i >> 5];
    __syncthreads();
    for (int i = t; i < 2048; i += 256) {
        int g = i >> 5, cc = i & 31;
        float a = bf1[cc];
        #pragma unroll
        for (int k = 0; k < 32; ++k) a += sg[g * 32 + k] * sW1[k * 32 + cc];
        st[i] = fmaxf(a, 0.f);
    }
    __syncthreads();
    for (int i = t; i < 640; i += 256) {
        int g = i / 10, o = i - g * 10;
        float a = bf2[o];
        #pragma unroll
        for (int k = 0; k < 32; ++k) a += st[g * 32 + k] * sW2[k * 10 + o];
        out[i] = a;
    }
}

extern "C" void kernel_launch(void* const* d_in, const int* in_sizes, int n_in,
                              void* d_out, int out_size, void* d_ws, size_t ws_size,
                              hipStream_t stream) {
    const float* x    = (const float*)d_in[0];
    const int*   ei   = (const int*)d_in[1];
    const int*   batch= (const int*)d_in[2];
    const float* W1   = (const float*)d_in[3];
    const float* as1  = (const float*)d_in[4];
    const float* ad1  = (const float*)d_in[5];
    const float* b1   = (const float*)d_in[6];
    const float* W2   = (const float*)d_in[7];
    const float* as2  = (const float*)d_in[8];
    const float* ad2  = (const float*)d_in[9];
    const float* b2   = (const float*)d_in[10];
    const float* W3r  = (const float*)d_in[11];
    const float* W3l  = (const float*)d_in[12];
    const float* b3   = (const float*)d_in[13];
    const float* W4l  = (const float*)d_in[14];
    const float* b4l  = (const float*)d_in[15];
    const float* W4r  = (const float*)d_in[16];
    const float* Wf1  = (const float*)d_in[17];
    const float* bf1  = (const float*)d_in[18];
    const float* Wf2  = (const float*)d_in[19];
    const float* bf2  = (const float*)d_in[20];

    const int N = in_sizes[0] / 128;
    const int E = in_sizes[1] / 2;
    const int* src = ei;
    const int* dst = ei + E;

    char* p = (char*)d_ws;
    auto alloc = [&](size_t bytes) -> void* {
        void* r = (void*)p;
        p += (bytes + 255) & ~(size_t)255;
        return r;
    };
    __hip_bfloat16* buf1 = (__hip_bfloat16*)alloc((size_t)N * 128 * 2);  // x2
    __hip_bfloat16* buf2 = (__hip_bfloat16*)alloc((size_t)N * 128 * 2);  // x1 / x3
    __hip_bfloat16* buf3 = (__hip_bfloat16*)alloc((size_t)N * 128 * 2);  // pairs / h1,h2 / y+root
    float* aS     = (float*)alloc((size_t)N * 4 * 4);
    float* aD     = (float*)alloc((size_t)N * 4 * 4);
    int*   rowptr = (int*)alloc((size_t)(N + 1) * 4);
    int*   colsrc = (int*)alloc((size_t)E * 4);
    int*   bbase  = (int*)alloc(257 * 4);
    int*   gcursor= (int*)alloc(256 * 4);
    int*   dcounter=(int*)alloc(4);
    __hip_bfloat16* W1t  = (__hip_bfloat16*)alloc(144 * 128 * 2);
    __hip_bfloat16* W2t  = (__hip_bfloat16*)alloc(144 * 128 * 2);
    __hip_bfloat16* W3rt = (__hip_bfloat16*)alloc(32 * 128 * 2);
    __hip_bfloat16* W3lt = (__hip_bfloat16*)alloc(32 * 128 * 2);
    float* gpool  = (float*)alloc(64 * 32 * 4);

    int nblkh = (E + 4095) / 4096;
    if (nblkh < 65) nblkh = 65;           // weight-prep needs blocks 1..64
    int* histg = (int*)alloc((size_t)nblkh * 256 * 4);

    // aliased views
    __hip_bfloat16* X3b  = buf2;                                        // N*32 bf16
    __hip_bfloat16* Y32  = buf3;                                        // N*32 bf16
    float*          ROOT = (float*)((char*)buf3 + (((size_t)N * 32 * 2 + 255) & ~(size_t)255));
    int*            pairs = (int*)buf3;   // E*4 B, consumed before h is written

    const int nbuck = (N + 255) >> 8;     // 196 for N=50000 (requires N<=65536)

    // ---- bucketed CSR build (atomic-free hist) + weight prep + zero-init ----
    bucket_hist<<<nblkh, 256, 0, stream>>>(dst, histg, E, nbuck, gpool, dcounter,
                                           W1, W2, W3r, W3l, as1, ad1, as2, ad2,
                                           W1t, W2t, W3rt, W3lt);
    scan_kernel<<<1, 256, 0, stream>>>(histg, nblkh, bbase, gcursor, nbuck, E, rowptr, N);
    bucket_scatter<<<(E + 2047) / 2048, 256, 0, stream>>>(dst, src, gcursor, pairs, E, nbuck);
    bucket_fill<<<nbuck, 256, 0, stream>>>(pairs, bbase, rowptr, colsrc, N);

    int gmm = (N + 63) / 64;
    if (gmm > 320) gmm = 320;                      // grid-stride GEMMs
    const int gag4  = (N + 15) / 16;               // gat_aggr: 4 dst/wave
    const int gag8  = (N + 31) / 32;               // 32-ch aggr: 8 dst/wave
    // GAT layer 1 (reads fp32 x directly)
    gemm_att_mfma<float><<<gmm, 256, 0, stream>>>(x, W1t, buf3, aS, aD, N);
    gat_aggr<<<gag4, 256, 0, stream>>>(buf3, aS, aD, rowptr, colsrc, b1, buf2, N);
    // GAT layer 2
    gemm_att_mfma<__hip_bfloat16><<<gmm, 256, 0, stream>>>(buf2, W2t, buf3, aS, aD, N);
    gat_aggr<<<gag4, 256, 0, stream>>>(buf3, aS, aD, rowptr, colsrc, b2, buf1, N);
    // GraphConv (project first, then 64B-row gather)
    graphconv_lin<<<gmm, 256, 0, stream>>>(buf1, W3rt, W3lt, b3, Y32, ROOT, N);
    graphconv_aggr<<<gag8, 256, 0, stream>>>(Y32, ROOT, rowptr, colsrc, X3b, N);
    // SAGE + pool + head fused (last block runs the MLP)
    sage_fused<<<gag8, 256, 0, stream>>>(X3b, rowptr, colsrc, W4l, b4l, W4r,
                                         batch, gpool, N,
                                         Wf1, bf1, Wf2, bf2, (float*)d_out, dcounter);
}

// Round 8
// 330.717 us; speedup vs baseline: 1.2489x; 1.2489x over previous
//
#include <hip/hip_runtime.h>
#include <hip/hip_bf16.h>
#include <type_traits>

// GNN: GAT(128->4x32) -> GAT(128->4x32) -> GraphConv(128->32) -> SAGE(32->32)
//      -> global mean pool (64 graphs) -> MLP(32->32->10)
// R7: bucketed CSR build (counting sort by dst>>8).         361 us
// R8: branchless gat_aggr; attention fused into GEMM.       359
// R9/R11: 4-deep gather pipeline, grid-stride GEMMs.        356
// R12: multi-dst-per-wave aggr.                             328.9
// R13: gat 4 dst/wave no-reduce, 32ch 8/wave.               327.9 (null)
// R14: sage_fused (mean+gemm+pool), 8-deep gat gather.      311.4
// R15: memset-free CSR build + head fused via last-block    413.0 REGRESSION
//     ticket. rocprof: sage_fused 130us, VALUBusy 6% -> the per-block
//     device-scope __threadfence (L2 writeback across 8 non-coherent XCD
//     L2s x 1563 blocks) serialized the dispatch. RULE: no grid-wide
//     fences as a fusion tool on multi-XCD CDNA.
// R16: surgical revert of the head fusion (separate head_kernel, R14's
//     sage_fused); keep R15's atomic-free hist + weight-prep-in-hist +
//     memset elimination (not implicated by counters).

typedef __bf16 v8bf __attribute__((ext_vector_type(8)));
typedef float  v4f  __attribute__((ext_vector_type(4)));

__device__ __forceinline__ float lrelu(float x) { return x > 0.f ? x : 0.2f * x; }

__device__ __forceinline__ unsigned short f2bf(float f) {
    unsigned u = __float_as_uint(f);
    unsigned r = (u + 0x7FFF + ((u >> 16) & 1)) >> 16;   // RNE
    return (unsigned short)r;
}
__device__ __forceinline__ float bfbits2f(unsigned short u) {
    return __uint_as_float((unsigned)u << 16);
}
__device__ __forceinline__ float bflo(int v) { return __uint_as_float((unsigned)v << 16); }
__device__ __forceinline__ float bfhi(int v) { return __uint_as_float((unsigned)v & 0xffff0000u); }
__device__ __forceinline__ int packbf2(float a, float b) {
    return (int)f2bf(a) | ((int)f2bf(b) << 16);
}

__device__ __forceinline__ void fma8(float* acc, int4 u, float w) {
    acc[0] += w * bflo(u.x); acc[1] += w * bfhi(u.x);
    acc[2] += w * bflo(u.y); acc[3] += w * bfhi(u.y);
    acc[4] += w * bflo(u.z); acc[5] += w * bfhi(u.z);
    acc[6] += w * bflo(u.w); acc[7] += w * bfhi(u.w);
}

// ================= bucketed CSR build =================
// bucket = dst >> 8 (256 dst per bucket); pairs word = (dst&255)<<17 | src.

// Per-block histogram dump (no global atomics) + weight prep (blocks 1..64)
// + gpool zeroing (block 0). Weight prep is dependency-free work hidden
// under the histogram pass.
__global__ __launch_bounds__(256) void bucket_hist(
    const int* __restrict__ dst, int* __restrict__ histg, int E, int nbuck,
    float* __restrict__ gpool,
    const float* __restrict__ W1, const float* __restrict__ W2,
    const float* __restrict__ W3r, const float* __restrict__ W3l,
    const float* __restrict__ as1, const float* __restrict__ ad1,
    const float* __restrict__ as2, const float* __restrict__ ad2,
    __hip_bfloat16* __restrict__ W1t, __hip_bfloat16* __restrict__ W2t,
    __hip_bfloat16* __restrict__ W3rt, __hip_bfloat16* __restrict__ W3lt)
{
    __shared__ int hist[256];
    int t = threadIdx.x;
    hist[t] = 0;
    __syncthreads();
    int base = blockIdx.x * 4096;
    #pragma unroll
    for (int k = 0; k < 16; ++k) {
        int e = base + k * 256 + t;
        if (e < E) atomicAdd(&hist[dst[e] >> 8], 1);
    }
    __syncthreads();
    histg[blockIdx.x * 256 + t] = hist[t];

    if (blockIdx.x == 0) {                  // zero pool accumulators
        for (int i = t; i < 64 * 32; i += 256) gpool[i] = 0.f;
    }
    if (blockIdx.x >= 1 && blockIdx.x <= 64) {
        int b = blockIdx.x - 1;             // 0..63
        int i = b * 256 + t;                // 0..16383
        {   // transpose W1/W2 into rows 0..127 of the 144-row layout
            int k = i >> 7, c = i & 127;
            *(unsigned short*)&W1t[c * 128 + k] = f2bf(W1[i]);
            *(unsigned short*)&W2t[c * 128 + k] = f2bf(W2[i]);
        }
        if (i < 4096) {
            int k = i >> 5, c = i & 31;
            *(unsigned short*)&W3rt[c * 128 + k] = f2bf(W3r[i]);
            *(unsigned short*)&W3lt[c * 128 + k] = f2bf(W3l[i]);
        }
        if (b == 0) {                       // attention-dot columns: 512 units
            for (int u = t; u < 512; u += 256) {
                int k = u & 127, hd = u >> 7;
                float vs1 = 0.f, vd1 = 0.f, vs2 = 0.f, vd2 = 0.f;
                #pragma unroll
                for (int j = 0; j < 32; ++j) {
                    int c = hd * 32 + j;
                    float w1 = W1[k * 128 + c], w2 = W2[k * 128 + c];
                    vs1 += w1 * as1[c]; vd1 += w1 * ad1[c];
                    vs2 += w2 * as2[c]; vd2 += w2 * ad2[c];
                }
                unsigned short h1s = f2bf(vs1), h1d = f2bf(vd1);
                unsigned short h2s = f2bf(vs2), h2d = f2bf(vd2);
                *(unsigned short*)&W1t[(128 + hd) * 128 + k] = h1s;
                *(unsigned short*)&W1t[(132 + hd) * 128 + k] = f2bf(vs1 - bfbits2f(h1s));
                *(unsigned short*)&W1t[(136 + hd) * 128 + k] = h1d;
                *(unsigned short*)&W1t[(140 + hd) * 128 + k] = f2bf(vd1 - bfbits2f(h1d));
                *(unsigned short*)&W2t[(128 + hd) * 128 + k] = h2s;
                *(unsigned short*)&W2t[(132 + hd) * 128 + k] = f2bf(vs2 - bfbits2f(h2s));
                *(unsigned short*)&W2t[(136 + hd) * 128 + k] = h2d;
                *(unsigned short*)&W2t[(140 + hd) * 128 + k] = f2bf(vd2 - bfbits2f(h2d));
            }
        }
    }
}

// 1-block scan over summed per-block histograms.
__global__ __launch_bounds__(256) void scan_kernel(
    const int* __restrict__ histg, int nblkh,
    int* __restrict__ bbase, int* __restrict__ gcursor,
    int nbuck, int E, int* __restrict__ rowptr, int n)
{
    __shared__ int red[256];
    int t = threadIdx.x;
    int v = 0;
    for (int b = 0; b < nblkh; ++b) v += histg[b * 256 + t];
    if (t >= nbuck) v = 0;
    red[t] = v;
    __syncthreads();
    for (int off = 1; off < 256; off <<= 1) {
        int u = (t >= off) ? red[t - off] : 0;
        __syncthreads();
        red[t] += u;
        __syncthreads();
    }
    int ex = red[t] - v;
    if (t < nbuck) { bbase[t] = ex; gcursor[t] = ex; }
    if (t == 0) { bbase[nbuck] = E; rowptr[n] = E; }
}

__global__ __launch_bounds__(256) void bucket_scatter(const int* __restrict__ dst,
                                                      const int* __restrict__ src,
                                                      int* __restrict__ gcursor,
                                                      int* __restrict__ pairs,
                                                      int E, int nbuck) {
    __shared__ int hist[256], lcur[256];
    int t = threadIdx.x;
    for (int i = t; i < nbuck; i += 256) hist[i] = 0;
    __syncthreads();
    int base = blockIdx.x * 2048;
    int dreg[8];
    #pragma unroll
    for (int k = 0; k < 8; ++k) {
        int e = base + k * 256 + t;
        int d = (e < E) ? dst[e] : -1;
        dreg[k] = d;
        if (d >= 0) atomicAdd(&hist[d >> 8], 1);
    }
    __syncthreads();
    for (int i = t; i < nbuck; i += 256) {
        int c = hist[i];
        lcur[i] = c ? atomicAdd(&gcursor[i], c) : 0;   // reserve contiguous run
    }
    __syncthreads();
    #pragma unroll
    for (int k = 0; k < 8; ++k) {
        int e = base + k * 256 + t;
        if (e < E) {
            int d = dreg[k];
            int p = atomicAdd(&lcur[d >> 8], 1);
            pairs[p] = ((d & 255) << 17) | src[e];
        }
    }
}

__global__ __launch_bounds__(256) void bucket_fill(const int* __restrict__ pairs,
                                                   const int* __restrict__ bbase,
                                                   int* __restrict__ rowptr,
                                                   int* __restrict__ colsrc, int n) {
    __shared__ int deg[256], excl[256], cur[256];
    int b = blockIdx.x, t = threadIdx.x;
    int e0 = bbase[b], e1 = bbase[b + 1];
    int d0 = b << 8;
    deg[t] = 0;
    __syncthreads();
    for (int j = e0 + t; j < e1; j += 256)
        atomicAdd(&deg[pairs[j] >> 17], 1);
    __syncthreads();
    int v = deg[t];
    excl[t] = v;
    __syncthreads();
    for (int off = 1; off < 256; off <<= 1) {
        int u = (t >= off) ? excl[t - off] : 0;
        __syncthreads();
        excl[t] += u;
        __syncthreads();
    }
    int base = e0 + excl[t] - v;                   // exclusive
    if (d0 + t < n) rowptr[d0 + t] = base;
    cur[t] = base;
    __syncthreads();
    for (int j = e0 + t; j < e1; j += 256) {
        int w = pairs[j];
        int p = atomicAdd(&cur[w >> 17], 1);
        colsrc[p] = w & 0x1FFFF;
    }
}

// ---------------- GAT GEMM via MFMA: [h | a_s | a_d] = X @ Wt(144 cols) ----------
// Grid-stride over 16-row tiles; weights staged in LDS once per block.
template <typename T>
__global__ __launch_bounds__(256) void gemm_att_mfma(
    const T* __restrict__ X, const __hip_bfloat16* __restrict__ Wt,
    __hip_bfloat16* __restrict__ h, float* __restrict__ a_s, float* __restrict__ a_d, int n)
{
    __shared__ __align__(16) __hip_bfloat16 sWt[144 * 136];   // [col][k], +8 pad
    int t = threadIdx.x;
    for (int i = t; i < 144 * 16; i += 256) {
        int row = i >> 4, chh = i & 15;
        *(int4*)&sWt[row * 136 + chh * 8] = *(const int4*)&Wt[row * 128 + chh * 8];
    }
    __syncthreads();
    int wave = t >> 6, lane = t & 63, quad = lane >> 4, l16 = lane & 15;

    v8bf z;
    #pragma unroll
    for (int i = 0; i < 8; ++i) z[i] = (__bf16)0.f;

    int nrb = (n + 15) >> 4;
    for (int rb = blockIdx.x * 4 + wave; rb < nrb; rb += gridDim.x * 4) {
        int rowbase = rb * 16;
        int arow = rowbase + l16;
        bool ok = arow < n;
        v8bf af[4];
        if constexpr (std::is_same<T, float>::value) {
            const float* xf = X + (size_t)(ok ? arow : 0) * 128;
            #pragma unroll
            for (int ks = 0; ks < 4; ++ks) {
                if (ok) {
                    float4 u = *(const float4*)&xf[ks * 32 + quad * 8];
                    float4 v = *(const float4*)&xf[ks * 32 + quad * 8 + 4];
                    v8bf a;
                    unsigned short r;
                    r = f2bf(u.x); a[0] = *(__bf16*)&r;
                    r = f2bf(u.y); a[1] = *(__bf16*)&r;
                    r = f2bf(u.z); a[2] = *(__bf16*)&r;
                    r = f2bf(u.w); a[3] = *(__bf16*)&r;
                    r = f2bf(v.x); a[4] = *(__bf16*)&r;
                    r = f2bf(v.y); a[5] = *(__bf16*)&r;
                    r = f2bf(v.z); a[6] = *(__bf16*)&r;
                    r = f2bf(v.w); a[7] = *(__bf16*)&r;
                    af[ks] = a;
                } else af[ks] = z;
            }
        } else {
            const v8bf* px = (const v8bf*)(X + (size_t)(ok ? arow : 0) * 128);
            #pragma unroll
            for (int ks = 0; ks < 4; ++ks) af[ks] = ok ? px[ks * 4 + quad] : z;
        }

        v4f acc[9];
        #pragma unroll
        for (int ct = 0; ct < 9; ++ct) acc[ct] = (v4f){0.f, 0.f, 0.f, 0.f};
        #pragma unroll
        for (int ct = 0; ct < 9; ++ct) {
            #pragma unroll
            for (int ks = 0; ks < 4; ++ks) {
                v8bf b = *(const v8bf*)&sWt[(ct * 16 + l16) * 136 + ks * 32 + quad * 8];
                acc[ct] = __builtin_amdgcn_mfma_f32_16x16x32_bf16(af[ks], b, acc[ct], 0, 0, 0);
            }
        }

        // h store (tiles 0..7): C layout col=l16, row=quad*4+reg
        #pragma unroll
        for (int reg = 0; reg < 4; ++reg) {
            int r = rowbase + quad * 4 + reg;
            if (r < n) {
                #pragma unroll
                for (int ct = 0; ct < 8; ++ct)
                    *(unsigned short*)&h[(size_t)r * 128 + ct * 16 + l16] = f2bf(acc[ct][reg]);
            }
        }
        // tile 8 = attention dots: cols l16: 0-3 s_hi, 4-7 s_lo, 8-11 d_hi, 12-15 d_lo
        #pragma unroll
        for (int reg = 0; reg < 4; ++reg) {
            float v = acc[8][reg] + __shfl_xor(acc[8][reg], 4);   // hi + lo
            int r = rowbase + quad * 4 + reg;
            if (r < n) {
                if (l16 < 4)                    a_s[r * 4 + l16] = v;
                else if (l16 >= 8 && l16 < 12)  a_d[r * 4 + (l16 - 8)] = v;
            }
        }
    }
}

// ---------------- GAT: 4 dst per wave (16 lanes each), 8-deep gather -------------
__global__ __launch_bounds__(256) void gat_aggr(
    const __hip_bfloat16* __restrict__ h, const float* __restrict__ a_s,
    const float* __restrict__ a_d,
    const int* __restrict__ rowptr, const int* __restrict__ colsrc,
    const float* __restrict__ bias, __hip_bfloat16* __restrict__ out, int n)
{
    __shared__ float s_w[4][4 * 16 * 4];           // [wave][q*64 + j*4 + head]
    int t = threadIdx.x;
    int wave = t >> 6, lane = t & 63;
    int q = lane >> 4, l16 = lane & 15;            // quarter = dst slot
    int d = blockIdx.x * 16 + wave * 4 + q;
    if (d >= n) d = n - 1;                         // duplicate work, benign
    int beg = rowptr[d];
    int cnt = rowptr[d + 1] - beg;
    int cm = max(cnt, __shfl_xor(cnt, 16));
    cm = max(cm, __shfl_xor(cm, 32));              // wave-uniform trip bound
    float4 ad4 = *(const float4*)&a_d[d * 4];
    float4 asd = *(const float4*)&a_s[d * 4];

    int ch = l16 * 8;                              // channels ch..ch+7
    int head = l16 >> 2;
    const char* hb = (const char*)h;
    unsigned chb = (unsigned)(ch << 1);            // byte offset within row
    int sbase = q * 64;                            // s_w base (floats)
    int lbase = q * 16;                            // shfl lane base

    float acc[8];
    #pragma unroll
    for (int i = 0; i < 8; ++i) acc[i] = 0.f;
    float zp = 0.f;                                // complete z for own head

    for (int j0 = 0; j0 < cm; j0 += 16) {
        int ne = cnt - j0;                         // own-dst remaining (may be <=0)
        float w0 = 0.f, w1 = 0.f, w2 = 0.f, w3 = 0.f;
        int s = 0;                                 // row 0 is a valid address
        if (l16 < ne) {
            s = colsrc[beg + j0 + l16];
            float4 sv = *(const float4*)&a_s[s * 4];
            w0 = __expf(lrelu(sv.x + ad4.x));
            w1 = __expf(lrelu(sv.y + ad4.y));
            w2 = __expf(lrelu(sv.z + ad4.z));
            w3 = __expf(lrelu(sv.w + ad4.w));
        }
        float4 wv = {w0, w1, w2, w3};              // zeros for pad lanes
        *(float4*)&s_w[wave][sbase + l16 * 4] = wv;
        __asm volatile("s_waitcnt lgkmcnt(0)" ::: "memory");  // wave-sync LDS
        // BRANCHLESS: s_w[j]==0 and s==0 for pad lanes / exhausted dsts.
        int nemax = cm - j0; if (nemax > 16) nemax = 16;
        int k = 0;
        for (; k + 8 <= nemax; k += 8) {           // 8 loads in flight per dst
            int   ss[8];
            float wj[8];
            int4  u[8];
            #pragma unroll
            for (int p2 = 0; p2 < 8; ++p2) {
                ss[p2] = __shfl(s, lbase + k + p2);
                wj[p2] = s_w[wave][sbase + (k + p2) * 4 + head];
            }
            #pragma unroll
            for (int p2 = 0; p2 < 8; ++p2)
                u[p2] = *(const int4*)(hb + (((unsigned)ss[p2] << 8) + chb));
            #pragma unroll
            for (int p2 = 0; p2 < 8; ++p2) { zp += wj[p2]; fma8(acc, u[p2], wj[p2]); }
        }
        for (; k + 4 <= nemax; k += 4) {           // 4-deep tail
            int ss0 = __shfl(s, lbase + k);
            int ss1 = __shfl(s, lbase + k + 1);
            int ss2 = __shfl(s, lbase + k + 2);
            int ss3 = __shfl(s, lbase + k + 3);
            float wj0 = s_w[wave][sbase + k * 4 + head];
            float wj1 = s_w[wave][sbase + (k + 1) * 4 + head];
            float wj2 = s_w[wave][sbase + (k + 2) * 4 + head];
            float wj3 = s_w[wave][sbase + (k + 3) * 4 + head];
            int4 u0 = *(const int4*)(hb + (((unsigned)ss0 << 8) + chb));
            int4 u1 = *(const int4*)(hb + (((unsigned)ss1 << 8) + chb));
            int4 u2 = *(const int4*)(hb + (((unsigned)ss2 << 8) + chb));
            int4 u3 = *(const int4*)(hb + (((unsigned)ss3 << 8) + chb));
            zp += (wj0 + wj1) + (wj2 + wj3);
            fma8(acc, u0, wj0);
            fma8(acc, u1, wj1);
            fma8(acc, u2, wj2);
            fma8(acc, u3, wj3);
        }
        for (; k < nemax; ++k) {                   // <=3 singles
            int ss0 = __shfl(s, lbase + k);
            float wj0 = s_w[wave][sbase + k * 4 + head];
            int4 u0 = *(const int4*)(hb + (((unsigned)ss0 << 8) + chb));
            zp += wj0;
            fma8(acc, u0, wj0);
        }
    }

    // epilogue: every lane writes 16B (16 lanes cover the 128-ch row)
    int4 hu = *(const int4*)(hb + (((unsigned)d << 8) + chb));
    float4 b0 = *(const float4*)&bias[ch];
    float4 b1 = *(const float4*)&bias[ch + 4];
    float eh0 = lrelu(asd.x + ad4.x), eh1 = lrelu(asd.y + ad4.y);
    float eh2 = lrelu(asd.z + ad4.z), eh3 = lrelu(asd.w + ad4.w);
    float eh = (head < 2) ? (head == 0 ? eh0 : eh1) : (head == 2 ? eh2 : eh3);
    float ws = __expf(eh);                         // self-loop weight
    float inv = 1.f / (zp + ws + 1e-16f);
    float hs[8] = {bflo(hu.x), bfhi(hu.x), bflo(hu.y), bfhi(hu.y),
                   bflo(hu.z), bfhi(hu.z), bflo(hu.w), bfhi(hu.w)};
    float o[8];
    o[0] = fmaxf((acc[0] + ws * hs[0]) * inv + b0.x, 0.f);
    o[1] = fmaxf((acc[1] + ws * hs[1]) * inv + b0.y, 0.f);
    o[2] = fmaxf((acc[2] + ws * hs[2]) * inv + b0.z, 0.f);
    o[3] = fmaxf((acc[3] + ws * hs[3]) * inv + b0.w, 0.f);
    o[4] = fmaxf((acc[4] + ws * hs[4]) * inv + b1.x, 0.f);
    o[5] = fmaxf((acc[5] + ws * hs[5]) * inv + b1.y, 0.f);
    o[6] = fmaxf((acc[6] + ws * hs[6]) * inv + b1.z, 0.f);
    o[7] = fmaxf((acc[7] + ws * hs[7]) * inv + b1.w, 0.f);
    int4 ou;
    ou.x = packbf2(o[0], o[1]); ou.y = packbf2(o[2], o[3]);
    ou.z = packbf2(o[4], o[5]); ou.w = packbf2(o[6], o[7]);
    *(int4*)&out[(size_t)d * 128 + ch] = ou;
}

// ---------------- GraphConv linear: y = x@Wr (bf16), root = x@Wl + b (fp32) -------
__global__ __launch_bounds__(256) void graphconv_lin(
    const __hip_bfloat16* __restrict__ Xb,
    const __hip_bfloat16* __restrict__ Wrt, const __hip_bfloat16* __restrict__ Wlt,
    const float* __restrict__ bias, __hip_bfloat16* __restrict__ y,
    float* __restrict__ root, int n)
{
    __shared__ __align__(16) __hip_bfloat16 sWr[32 * 136], sWl[32 * 136];
    int t = threadIdx.x;
    for (int i = t; i < 32 * 16; i += 256) {
        int row = i >> 4, chh = i & 15;
        *(int4*)&sWr[row * 136 + chh * 8] = *(const int4*)&Wrt[row * 128 + chh * 8];
        *(int4*)&sWl[row * 136 + chh * 8] = *(const int4*)&Wlt[row * 128 + chh * 8];
    }
    __syncthreads();
    int wave = t >> 6, lane = t & 63, quad = lane >> 4, l16 = lane & 15;

    v8bf z;
    #pragma unroll
    for (int i = 0; i < 8; ++i) z[i] = (__bf16)0.f;

    int nrb = (n + 15) >> 4;
    for (int rb = blockIdx.x * 4 + wave; rb < nrb; rb += gridDim.x * 4) {
        int rowbase = rb * 16;
        int arow = rowbase + l16;
        bool ok = arow < n;
        const v8bf* px = (const v8bf*)(Xb + (size_t)(ok ? arow : 0) * 128);
        v8bf fx[4];
        #pragma unroll
        for (int ks = 0; ks < 4; ++ks) fx[ks] = ok ? px[ks * 4 + quad] : z;

        v4f accR[2], accL[2];
        #pragma unroll
        for (int ct = 0; ct < 2; ++ct) {
            accR[ct] = (v4f){0.f, 0.f, 0.f, 0.f};
            accL[ct] = (v4f){0.f, 0.f, 0.f, 0.f};
            #pragma unroll
            for (int ks = 0; ks < 4; ++ks) {
                v8bf br = *(const v8bf*)&sWr[(ct * 16 + l16) * 136 + ks * 32 + quad * 8];
                accR[ct] = __builtin_amdgcn_mfma_f32_16x16x32_bf16(fx[ks], br, accR[ct], 0, 0, 0);
                v8bf bl = *(const v8bf*)&sWl[(ct * 16 + l16) * 136 + ks * 32 + quad * 8];
                accL[ct] = __builtin_amdgcn_mfma_f32_16x16x32_bf16(fx[ks], bl, accL[ct], 0, 0, 0);
            }
        }
        #pragma unroll
        for (int ct = 0; ct < 2; ++ct) {
            float bcol = bias[ct * 16 + l16];
            #pragma unroll
            for (int reg = 0; reg < 4; ++reg) {
                int r = rowbase + quad * 4 + reg;
                if (r < n) {
                    *(unsigned short*)&y[(size_t)r * 32 + ct * 16 + l16] = f2bf(accR[ct][reg]);
                    root[(size_t)r * 32 + ct * 16 + l16] = accL[ct][reg] + bcol;
                }
            }
        }
    }
}

// ---------------- GraphConv aggr: 8 dst per wave (8 lanes each), 32 ch -----------
__global__ __launch_bounds__(256) void graphconv_aggr(
    const __hip_bfloat16* __restrict__ y, const float* __restrict__ root,
    const int* __restrict__ rowptr, const int* __restrict__ colsrc,
    __hip_bfloat16* __restrict__ x3, int n)
{
    int t = threadIdx.x;
    int wave = t >> 6, lane = t & 63;
    int oct = lane >> 3, ol = lane & 7;            // octet = dst slot
    int d = blockIdx.x * 32 + wave * 8 + oct;
    if (d >= n) d = n - 1;
    int beg = rowptr[d];
    int cnt = rowptr[d + 1] - beg;
    int cm = max(cnt, __shfl_xor(cnt, 8));
    cm = max(cm, __shfl_xor(cm, 16));
    cm = max(cm, __shfl_xor(cm, 32));              // wave-uniform trip bound
    int l4 = ol & 3, egrp = ol >> 2;               // 2 edge-groups x 4 ch-lanes
    int ch = l4 * 8;
    int lbase = oct * 8;
    float acc[8];
    #pragma unroll
    for (int i = 0; i < 8; ++i) acc[i] = 0.f;
    for (int j0 = 0; j0 < cm; j0 += 8) {
        int ne = cnt - j0;                         // own-dst remaining
        int s = (ol < ne) ? colsrc[beg + j0 + ol] : 0;
        int nemax = cm - j0; if (nemax > 8) nemax = 8;
        int kmax = (nemax + 1) >> 1;               // uniform trip count
        int k = 0;
        for (; k + 2 <= kmax; k += 2) {            // 4 edges in flight
            int ja = egrp + 2 * k, jb = ja + 2;
            int sa = __shfl(s, lbase + ja);
            int sb = __shfl(s, lbase + jb);
            float ma = (ja < ne) ? 1.f : 0.f;      // branchless mask (own dst)
            float mb = (jb < ne) ? 1.f : 0.f;
            int4 ua = *(const int4*)&y[(size_t)sa * 32 + ch];
            int4 ub = *(const int4*)&y[(size_t)sb * 32 + ch];
            fma8(acc, ua, ma);
            fma8(acc, ub, mb);
        }
        if (k < kmax) {
            int ja = egrp + 2 * k;
            int sa = __shfl(s, lbase + ja);
            float ma = (ja < ne) ? 1.f : 0.f;
            int4 ua = *(const int4*)&y[(size_t)sa * 32 + ch];
            fma8(acc, ua, ma);
        }
    }
    float4 r0 = {0.f, 0.f, 0.f, 0.f}, r1 = {0.f, 0.f, 0.f, 0.f};
    if (egrp == 0) {                               // hoist above reduction
        r0 = *(const float4*)&root[(size_t)d * 32 + ch];
        r1 = *(const float4*)&root[(size_t)d * 32 + ch + 4];
    }
    #pragma unroll
    for (int i = 0; i < 8; ++i) acc[i] += __shfl_xor(acc[i], 4);   // combine 2 groups
    if (egrp == 0) {                               // 4 lanes per dst write 16B each
        float o[8];
        o[0] = fmaxf(acc[0] + r0.x, 0.f); o[1] = fmaxf(acc[1] + r0.y, 0.f);
        o[2] = fmaxf(acc[2] + r0.z, 0.f); o[3] = fmaxf(acc[3] + r0.w, 0.f);
        o[4] = fmaxf(acc[4] + r1.x, 0.f); o[5] = fmaxf(acc[5] + r1.y, 0.f);
        o[6] = fmaxf(acc[6] + r1.z, 0.f); o[7] = fmaxf(acc[7] + r1.w, 0.f);
        int4 ou;
        ou.x = packbf2(o[0], o[1]); ou.y = packbf2(o[2], o[3]);
        ou.z = packbf2(o[4], o[5]); ou.w = packbf2(o[6], o[7]);
        *(int4*)&x3[(size_t)d * 32 + ch] = ou;
    }
}

// ---------------- SAGE fused: mean-gather + 32x32 GEMM + global-mean-pool --------
// Block = 32 dsts (8 dst/wave gather). Means land in LDS; out = relu(mean@Wl
// + bl + x3@Wr) computed in-block; per-graph pool partials accumulated in LDS
// and flushed with one atomicAdd per (graph,channel) per block. NO grid-wide
// fence (R15 lesson: device-scope threadfence per block = 100us on 8 XCDs).
__global__ __launch_bounds__(256) void sage_fused(
    const __hip_bfloat16* __restrict__ x3, const int* __restrict__ rowptr,
    const int* __restrict__ colsrc,
    const float* __restrict__ Wl, const float* __restrict__ bl,
    const float* __restrict__ Wr,
    const int* __restrict__ batch, float* __restrict__ gpool, int n)
{
    __shared__ __align__(16) float sWl[32 * 32], sWr[32 * 32];
    __shared__ __align__(16) float smean[32 * 32], sx[32 * 32];
    __shared__ float sacc[64 * 32];                // per-graph pool partials
    __shared__ int sbat[32];
    int t = threadIdx.x;
    int row0 = blockIdx.x * 32;
    for (int i = t; i < 1024; i += 256) {
        sWl[i] = Wl[i]; sWr[i] = Wr[i];
    }
    for (int i = t; i < 2048; i += 256) sacc[i] = 0.f;
    if (t < 32) sbat[t] = batch[min(row0 + t, n - 1)];

    // ---- gather phase: 8 dst per wave, mean into LDS ----
    int wave = t >> 6, lane = t & 63;
    int oct = lane >> 3, ol = lane & 7;
    int slot = wave * 8 + oct;                     // 0..31
    int d = row0 + slot;
    if (d >= n) d = n - 1;
    int beg = rowptr[d];
    int cnt = rowptr[d + 1] - beg;
    int cm = max(cnt, __shfl_xor(cnt, 8));
    cm = max(cm, __shfl_xor(cm, 16));
    cm = max(cm, __shfl_xor(cm, 32));
    int l4 = ol & 3, egrp = ol >> 2;
    int ch = l4 * 8;
    int lbase = oct * 8;
    float acc[8];
    #pragma unroll
    for (int i = 0; i < 8; ++i) acc[i] = 0.f;
    for (int j0 = 0; j0 < cm; j0 += 8) {
        int ne = cnt - j0;
        int s = (ol < ne) ? colsrc[beg + j0 + ol] : 0;
        int nemax = cm - j0; if (nemax > 8) nemax = 8;
        int kmax = (nemax + 1) >> 1;
        int k = 0;
        for (; k + 2 <= kmax; k += 2) {
            int ja = egrp + 2 * k, jb = ja + 2;
            int sa = __shfl(s, lbase + ja);
            int sb = __shfl(s, lbase + jb);
            float ma = (ja < ne) ? 1.f : 0.f;
            float mb = (jb < ne) ? 1.f : 0.f;
            int4 ua = *(const int4*)&x3[(size_t)sa * 32 + ch];
            int4 ub = *(const int4*)&x3[(size_t)sb * 32 + ch];
            fma8(acc, ua, ma);
            fma8(acc, ub, mb);
        }
        if (k < kmax) {
            int ja = egrp + 2 * k;
            int sa = __shfl(s, lbase + ja);
            float ma = (ja < ne) ? 1.f : 0.f;
            int4 ua = *(const int4*)&x3[(size_t)sa * 32 + ch];
            fma8(acc, ua, ma);
        }
    }
    #pragma unroll
    for (int i = 0; i < 8; ++i) acc[i] += __shfl_xor(acc[i], 4);
    if (egrp == 0) {                               // stage mean + own x3 row
        float invd = 1.f / fmaxf((float)cnt, 1.f);
        float4 lo = {acc[0] * invd, acc[1] * invd, acc[2] * invd, acc[3] * invd};
        float4 hi = {acc[4] * invd, acc[5] * invd, acc[6] * invd, acc[7] * invd};
        *(float4*)&smean[slot * 32 + ch]     = lo;
        *(float4*)&smean[slot * 32 + ch + 4] = hi;
        int4 xu = *(const int4*)&x3[(size_t)d * 32 + ch];
        float4 x0 = {bflo(xu.x), bfhi(xu.x), bflo(xu.y), bfhi(xu.y)};
        float4 x1 = {bflo(xu.z), bfhi(xu.z), bflo(xu.w), bfhi(xu.w)};
        *(float4*)&sx[slot * 32 + ch]     = x0;
        *(float4*)&sx[slot * 32 + ch + 4] = x1;
    }
    __syncthreads();

    // ---- GEMM + pool-accumulate: thread (c = t&31) does rows rr, rr+8, ... ----
    int c = t & 31, rr = t >> 5;
    float bc = bl[c];
    int gbase = sbat[0];
    #pragma unroll
    for (int kr = 0; kr < 4; ++kr) {
        int r = rr + 8 * kr;
        float a = bc;
        const float4* pm = (const float4*)&smean[r * 32];
        const float4* px = (const float4*)&sx[r * 32];
        #pragma unroll
        for (int k4 = 0; k4 < 8; ++k4) {
            float4 vm = pm[k4], vx = px[k4];
            const float* wl = &sWl[(k4 * 4) * 32 + c];
            const float* wr = &sWr[(k4 * 4) * 32 + c];
            a += vm.x * wl[0] + vm.y * wl[32] + vm.z * wl[64] + vm.w * wl[96];
            a += vx.x * wr[0] + vx.y * wr[32] + vx.z * wr[64] + vx.w * wr[96];
        }
        float v = fmaxf(a, 0.f);
        int row = row0 + r;
        if (row < n) atomicAdd(&sacc[(sbat[r] - gbase) * 32 + c], v);
    }
    __syncthreads();
    int ngr = sbat[31] - gbase + 1;                // graphs spanned by this block
    for (int i = t; i < ngr * 32; i += 256) {
        float v = sacc[i];
        if (v != 0.f) atomicAdd(&gpool[(size_t)gbase * 32 + i], v);
    }
}

// ---------------- MLP head (divides pool sums by per-graph counts) ---------------
__device__ __forceinline__ int lower_bound_i(const int* a, int n, int key) {
    int lo = 0, hi = n;
    while (lo < hi) { int mid = (lo + hi) >> 1; if (a[mid] < key) lo = mid + 1; else hi = mid; }
    return lo;
}

__global__ __launch_bounds__(256) void head_kernel(
    const float* __restrict__ gpool, const int* __restrict__ batch, int n,
    const float* __restrict__ Wf1, const float* __restrict__ bf1,
    const float* __restrict__ Wf2, const float* __restrict__ bf2, float* __restrict__ out)
{
    __shared__ float sg[64 * 32], st[64 * 32];
    __shared__ float sW1[32 * 32], sW2[32 * 10];
    __shared__ float sinv[64];
    int t = threadIdx.x;
    if (t < 64) {
        int lo = lower_bound_i(batch, n, t);
        int hi = lower_bound_i(batch, n, t + 1);
        sinv[t] = 1.f / fmaxf((float)(hi - lo), 1.f);
    }
    for (int i = t; i < 1024; i += 256) sW1[i] = Wf1[i];
    for (int i = t; i < 320; i += 256) sW2[i] = Wf2[i];
    __syncthreads();
    for (int i = t; i < 2048; i += 256) sg[i] = gpool[i] * sinv[i >> 5];
    __syncthreads();
    for (int i = t; i < 2048; i += 256) {
        int g = i >> 5, c = i & 31;
        float acc = bf1[c];
        #pragma unroll
        for (int k = 0; k < 32; ++k) acc += sg[g * 32 + k] * sW1[k * 32 + c];
        st[i] = fmaxf(acc, 0.f);
    }
    __syncthreads();
    for (int i = t; i < 640; i += 256) {
        int g = i / 10, o = i - g * 10;
        float acc = bf2[o];
        #pragma unroll
        for (int k = 0; k < 32; ++k) acc += st[g * 32 + k] * sW2[k * 10 + o];
        out[i] = acc;
    }
}

extern "C" void kernel_launch(void* const* d_in, const int* in_sizes, int n_in,
                              void* d_out, int out_size, void* d_ws, size_t ws_size,
                              hipStream_t stream) {
    const float* x    = (const float*)d_in[0];
    const int*   ei   = (const int*)d_in[1];
    const int*   batch= (const int*)d_in[2];
    const float* W1   = (const float*)d_in[3];
    const float* as1  = (const float*)d_in[4];
    const float* ad1  = (const float*)d_in[5];
    const float* b1   = (const float*)d_in[6];
    const float* W2   = (const float*)d_in[7];
    const float* as2  = (const float*)d_in[8];
    const float* ad2  = (const float*)d_in[9];
    const float* b2   = (const float*)d_in[10];
    const float* W3r  = (const float*)d_in[11];
    const float* W3l  = (const float*)d_in[12];
    const float* b3   = (const float*)d_in[13];
    const float* W4l  = (const float*)d_in[14];
    const float* b4l  = (const float*)d_in[15];
    const float* W4r  = (const float*)d_in[16];
    const float* Wf1  = (const float*)d_in[17];
    const float* bf1  = (const float*)d_in[18];
    const float* Wf2  = (const float*)d_in[19];
    const float* bf2  = (const float*)d_in[20];

    const int N = in_sizes[0] / 128;
    const int E = in_sizes[1] / 2;
    const int* src = ei;
    const int* dst = ei + E;

    char* p = (char*)d_ws;
    auto alloc = [&](size_t bytes) -> void* {
        void* r = (void*)p;
        p += (bytes + 255) & ~(size_t)255;
        return r;
    };
    __hip_bfloat16* buf1 = (__hip_bfloat16*)alloc((size_t)N * 128 * 2);  // x2
    __hip_bfloat16* buf2 = (__hip_bfloat16*)alloc((size_t)N * 128 * 2);  // x1 / x3
    __hip_bfloat16* buf3 = (__hip_bfloat16*)alloc((size_t)N * 128 * 2);  // pairs / h1,h2 / y+root
    float* aS     = (float*)alloc((size_t)N * 4 * 4);
    float* aD     = (float*)alloc((size_t)N * 4 * 4);
    int*   rowptr = (int*)alloc((size_t)(N + 1) * 4);
    int*   colsrc = (int*)alloc((size_t)E * 4);
    int*   bbase  = (int*)alloc(257 * 4);
    int*   gcursor= (int*)alloc(256 * 4);
    __hip_bfloat16* W1t  = (__hip_bfloat16*)alloc(144 * 128 * 2);
    __hip_bfloat16* W2t  = (__hip_bfloat16*)alloc(144 * 128 * 2);
    __hip_bfloat16* W3rt = (__hip_bfloat16*)alloc(32 * 128 * 2);
    __hip_bfloat16* W3lt = (__hip_bfloat16*)alloc(32 * 128 * 2);
    float* gpool  = (float*)alloc(64 * 32 * 4);

    int nblkh = (E + 4095) / 4096;
    if (nblkh < 65) nblkh = 65;           // weight-prep needs blocks 1..64
    int* histg = (int*)alloc((size_t)nblkh * 256 * 4);

    // aliased views
    __hip_bfloat16* X3b  = buf2;                                        // N*32 bf16
    __hip_bfloat16* Y32  = buf3;                                        // N*32 bf16
    float*          ROOT = (float*)((char*)buf3 + (((size_t)N * 32 * 2 + 255) & ~(size_t)255));
    int*            pairs = (int*)buf3;   // E*4 B, consumed before h is written

    const int nbuck = (N + 255) >> 8;     // 196 for N=50000 (requires N<=65536)

    // ---- bucketed CSR build (atomic-free hist) + weight prep + zero-init ----
    bucket_hist<<<nblkh, 256, 0, stream>>>(dst, histg, E, nbuck, gpool,
                                           W1, W2, W3r, W3l, as1, ad1, as2, ad2,
                                           W1t, W2t, W3rt, W3lt);
    scan_kernel<<<1, 256, 0, stream>>>(histg, nblkh, bbase, gcursor, nbuck, E, rowptr, N);
    bucket_scatter<<<(E + 2047) / 2048, 256, 0, stream>>>(dst, src, gcursor, pairs, E, nbuck);
    bucket_fill<<<nbuck, 256, 0, stream>>>(pairs, bbase, rowptr, colsrc, N);

    int gmm = (N + 63) / 64;
    if (gmm > 320) gmm = 320;                      // grid-stride GEMMs
    const int gag4  = (N + 15) / 16;               // gat_aggr: 4 dst/wave
    const int gag8  = (N + 31) / 32;               // 32-ch aggr: 8 dst/wave
    // GAT layer 1 (reads fp32 x directly)
    gemm_att_mfma<float><<<gmm, 256, 0, stream>>>(x, W1t, buf3, aS, aD, N);
    gat_aggr<<<gag4, 256, 0, stream>>>(buf3, aS, aD, rowptr, colsrc, b1, buf2, N);
    // GAT layer 2
    gemm_att_mfma<__hip_bfloat16><<<gmm, 256, 0, stream>>>(buf2, W2t, buf3, aS, aD, N);
    gat_aggr<<<gag4, 256, 0, stream>>>(buf3, aS, aD, rowptr, colsrc, b2, buf1, N);
    // GraphConv (project first, then 64B-row gather)
    graphconv_lin<<<gmm, 256, 0, stream>>>(buf1, W3rt, W3lt, b3, Y32, ROOT, N);
    graphconv_aggr<<<gag8, 256, 0, stream>>>(Y32, ROOT, rowptr, colsrc, X3b, N);
    // SAGE + pool fused (mean gather -> 32x32 GEMM -> per-graph pool sums)
    sage_fused<<<gag8, 256, 0, stream>>>(X3b, rowptr, colsrc, W4l, b4l, W4r,
                                         batch, gpool, N);
    // head (divides pool sums by counts)
    head_kernel<<<1, 256, 0, stream>>>(gpool, batch, N, Wf1, bf1, Wf2, bf2, (float*)d_out);
}

// Round 10
// 309.059 us; speedup vs baseline: 1.3364x; 1.0701x over previous
//
#include <hip/hip_runtime.h>
#include <hip/hip_bf16.h>
#include <type_traits>

// GNN: GAT(128->4x32) -> GAT(128->4x32) -> GraphConv(128->32) -> SAGE(32->32)
//      -> global mean pool (64 graphs) -> MLP(32->32->10)
// R7: bucketed CSR build (counting sort by dst>>8).         361 us
// R8: branchless gat_aggr; attention fused into GEMM.       359
// R9/R11: 4-deep gather pipeline, grid-stride GEMMs.        356
// R12: multi-dst-per-wave aggr.                             328.9
// R13: gat 4 dst/wave no-reduce, 32ch 8/wave.               327.9 (null)
// R14: sage_fused (mean+gemm+pool), 8-deep gat gather.      311.4  <- BEST
// R15: head fused via last-block ticket + CSR restructure.  413.0 REGRESSION
//     (device-scope threadfence x 1563 blocks serialized on 8 XCDs)
// R16: partial revert, kept R15 CSR restructure.            330.7 REGRESSION
// R17: FULL revert to measured-best R14 config + merged memset (-1 dispatch).
// R18: resubmit of R17 (round-9 bench was an infra container failure,
//     same signature as rounds 1-2 which passed unchanged on retry).

typedef __bf16 v8bf __attribute__((ext_vector_type(8)));
typedef float  v4f  __attribute__((ext_vector_type(4)));

__device__ __forceinline__ float lrelu(float x) { return x > 0.f ? x : 0.2f * x; }

__device__ __forceinline__ unsigned short f2bf(float f) {
    unsigned u = __float_as_uint(f);
    unsigned r = (u + 0x7FFF + ((u >> 16) & 1)) >> 16;   // RNE
    return (unsigned short)r;
}
__device__ __forceinline__ float bfbits2f(unsigned short u) {
    return __uint_as_float((unsigned)u << 16);
}
__device__ __forceinline__ float bflo(int v) { return __uint_as_float((unsigned)v << 16); }
__device__ __forceinline__ float bfhi(int v) { return __uint_as_float((unsigned)v & 0xffff0000u); }
__device__ __forceinline__ int packbf2(float a, float b) {
    return (int)f2bf(a) | ((int)f2bf(b) << 16);
}

__device__ __forceinline__ void fma8(float* acc, int4 u, float w) {
    acc[0] += w * bflo(u.x); acc[1] += w * bfhi(u.x);
    acc[2] += w * bflo(u.y); acc[3] += w * bfhi(u.y);
    acc[4] += w * bflo(u.z); acc[5] += w * bfhi(u.z);
    acc[6] += w * bflo(u.w); acc[7] += w * bfhi(u.w);
}

// ================= bucketed CSR build =================
// bucket = dst >> 8 (256 dst per bucket); pairs word = (dst&255)<<17 | src.

__global__ __launch_bounds__(256) void bucket_hist(const int* __restrict__ dst,
                                                   int* __restrict__ bcount,
                                                   int E, int nbuck) {
    __shared__ int hist[256];
    int t = threadIdx.x;
    for (int i = t; i < nbuck; i += 256) hist[i] = 0;
    __syncthreads();
    int base = blockIdx.x * 4096;
    #pragma unroll
    for (int k = 0; k < 16; ++k) {
        int e = base + k * 256 + t;
        if (e < E) atomicAdd(&hist[dst[e] >> 8], 1);
    }
    __syncthreads();
    for (int i = t; i < nbuck; i += 256) {
        int c = hist[i];
        if (c) atomicAdd(&bcount[i], c);
    }
}

// block 0: scan bucket counts. blocks 1..64: weight prep (transpose+bf16 and
// attention-dot columns Vs/Vd in hi+lo bf16 split appended as rows 128..143).
__global__ __launch_bounds__(256) void scan_convert(
    const int* __restrict__ bcount, int* __restrict__ bbase, int* __restrict__ gcursor,
    int nbuck, int E, int* __restrict__ rowptr, int n,
    const float* __restrict__ W1, const float* __restrict__ W2,
    const float* __restrict__ W3r, const float* __restrict__ W3l,
    const float* __restrict__ as1, const float* __restrict__ ad1,
    const float* __restrict__ as2, const float* __restrict__ ad2,
    __hip_bfloat16* __restrict__ W1t, __hip_bfloat16* __restrict__ W2t,
    __hip_bfloat16* __restrict__ W3rt, __hip_bfloat16* __restrict__ W3lt)
{
    int t = threadIdx.x;
    if (blockIdx.x == 0) {
        __shared__ int red[256];
        int v = (t < nbuck) ? bcount[t] : 0;
        red[t] = v;
        __syncthreads();
        for (int off = 1; off < 256; off <<= 1) {
            int u = (t >= off) ? red[t - off] : 0;
            __syncthreads();
            red[t] += u;
            __syncthreads();
        }
        int ex = red[t] - v;
        if (t < nbuck) { bbase[t] = ex; gcursor[t] = ex; }
        if (t == 0) { bbase[nbuck] = E; rowptr[n] = E; }
        return;
    }
    int b = blockIdx.x - 1;                 // 0..63
    int i = b * 256 + t;                    // 0..16383
    {   // transpose W1/W2 into rows 0..127 of the 144-row layout
        int k = i >> 7, c = i & 127;
        *(unsigned short*)&W1t[c * 128 + k] = f2bf(W1[i]);
        *(unsigned short*)&W2t[c * 128 + k] = f2bf(W2[i]);
    }
    if (i < 4096) {
        int k = i >> 5, c = i & 31;
        *(unsigned short*)&W3rt[c * 128 + k] = f2bf(W3r[i]);
        *(unsigned short*)&W3lt[c * 128 + k] = f2bf(W3l[i]);
    }
    if (b == 0) {                           // attention-dot columns: 512 units
        for (int u = t; u < 512; u += 256) {
            int k = u & 127, hd = u >> 7;
            float vs1 = 0.f, vd1 = 0.f, vs2 = 0.f, vd2 = 0.f;
            #pragma unroll
            for (int j = 0; j < 32; ++j) {
                int c = hd * 32 + j;
                float w1 = W1[k * 128 + c], w2 = W2[k * 128 + c];
                vs1 += w1 * as1[c]; vd1 += w1 * ad1[c];
                vs2 += w2 * as2[c]; vd2 += w2 * ad2[c];
            }
            unsigned short h1s = f2bf(vs1), h1d = f2bf(vd1);
            unsigned short h2s = f2bf(vs2), h2d = f2bf(vd2);
            *(unsigned short*)&W1t[(128 + hd) * 128 + k] = h1s;
            *(unsigned short*)&W1t[(132 + hd) * 128 + k] = f2bf(vs1 - bfbits2f(h1s));
            *(unsigned short*)&W1t[(136 + hd) * 128 + k] = h1d;
            *(unsigned short*)&W1t[(140 + hd) * 128 + k] = f2bf(vd1 - bfbits2f(h1d));
            *(unsigned short*)&W2t[(128 + hd) * 128 + k] = h2s;
            *(unsigned short*)&W2t[(132 + hd) * 128 + k] = f2bf(vs2 - bfbits2f(h2s));
            *(unsigned short*)&W2t[(136 + hd) * 128 + k] = h2d;
            *(unsigned short*)&W2t[(140 + hd) * 128 + k] = f2bf(vd2 - bfbits2f(h2d));
        }
    }
}

__global__ __launch_bounds__(256) void bucket_scatter(const int* __restrict__ dst,
                                                      const int* __restrict__ src,
                                                      int* __restrict__ gcursor,
                                                      int* __restrict__ pairs,
                                                      int E, int nbuck) {
    __shared__ int hist[256], lcur[256];
    int t = threadIdx.x;
    for (int i = t; i < nbuck; i += 256) hist[i] = 0;
    __syncthreads();
    int base = blockIdx.x * 2048;
    int dreg[8];
    #pragma unroll
    for (int k = 0; k < 8; ++k) {
        int e = base + k * 256 + t;
        int d = (e < E) ? dst[e] : -1;
        dreg[k] = d;
        if (d >= 0) atomicAdd(&hist[d >> 8], 1);
    }
    __syncthreads();
    for (int i = t; i < nbuck; i += 256) {
        int c = hist[i];
        lcur[i] = c ? atomicAdd(&gcursor[i], c) : 0;   // reserve contiguous run
    }
    __syncthreads();
    #pragma unroll
    for (int k = 0; k < 8; ++k) {
        int e = base + k * 256 + t;
        if (e < E) {
            int d = dreg[k];
            int p = atomicAdd(&lcur[d >> 8], 1);
            pairs[p] = ((d & 255) << 17) | src[e];
        }
    }
}

__global__ __launch_bounds__(256) void bucket_fill(const int* __restrict__ pairs,
                                                   const int* __restrict__ bbase,
                                                   int* __restrict__ rowptr,
                                                   int* __restrict__ colsrc, int n) {
    __shared__ int deg[256], excl[256], cur[256];
    int b = blockIdx.x, t = threadIdx.x;
    int e0 = bbase[b], e1 = bbase[b + 1];
    int d0 = b << 8;
    deg[t] = 0;
    __syncthreads();
    for (int j = e0 + t; j < e1; j += 256)
        atomicAdd(&deg[pairs[j] >> 17], 1);
    __syncthreads();
    int v = deg[t];
    excl[t] = v;
    __syncthreads();
    for (int off = 1; off < 256; off <<= 1) {
        int u = (t >= off) ? excl[t - off] : 0;
        __syncthreads();
        excl[t] += u;
        __syncthreads();
    }
    int base = e0 + excl[t] - v;                   // exclusive
    if (d0 + t < n) rowptr[d0 + t] = base;
    cur[t] = base;
    __syncthreads();
    for (int j = e0 + t; j < e1; j += 256) {
        int w = pairs[j];
        int p = atomicAdd(&cur[w >> 17], 1);
        colsrc[p] = w & 0x1FFFF;
    }
}

// ---------------- GAT GEMM via MFMA: [h | a_s | a_d] = X @ Wt(144 cols) ----------
// Grid-stride over 16-row tiles; weights staged in LDS once per block.
template <typename T>
__global__ __launch_bounds__(256) void gemm_att_mfma(
    const T* __restrict__ X, const __hip_bfloat16* __restrict__ Wt,
    __hip_bfloat16* __restrict__ h, float* __restrict__ a_s, float* __restrict__ a_d, int n)
{
    __shared__ __align__(16) __hip_bfloat16 sWt[144 * 136];   // [col][k], +8 pad
    int t = threadIdx.x;
    for (int i = t; i < 144 * 16; i += 256) {
        int row = i >> 4, chh = i & 15;
        *(int4*)&sWt[row * 136 + chh * 8] = *(const int4*)&Wt[row * 128 + chh * 8];
    }
    __syncthreads();
    int wave = t >> 6, lane = t & 63, quad = lane >> 4, l16 = lane & 15;

    v8bf z;
    #pragma unroll
    for (int i = 0; i < 8; ++i) z[i] = (__bf16)0.f;

    int nrb = (n + 15) >> 4;
    for (int rb = blockIdx.x * 4 + wave; rb < nrb; rb += gridDim.x * 4) {
        int rowbase = rb * 16;
        int arow = rowbase + l16;
        bool ok = arow < n;
        v8bf af[4];
        if constexpr (std::is_same<T, float>::value) {
            const float* xf = X + (size_t)(ok ? arow : 0) * 128;
            #pragma unroll
            for (int ks = 0; ks < 4; ++ks) {
                if (ok) {
                    float4 u = *(const float4*)&xf[ks * 32 + quad * 8];
                    float4 v = *(const float4*)&xf[ks * 32 + quad * 8 + 4];
                    v8bf a;
                    unsigned short r;
                    r = f2bf(u.x); a[0] = *(__bf16*)&r;
                    r = f2bf(u.y); a[1] = *(__bf16*)&r;
                    r = f2bf(u.z); a[2] = *(__bf16*)&r;
                    r = f2bf(u.w); a[3] = *(__bf16*)&r;
                    r = f2bf(v.x); a[4] = *(__bf16*)&r;
                    r = f2bf(v.y); a[5] = *(__bf16*)&r;
                    r = f2bf(v.z); a[6] = *(__bf16*)&r;
                    r = f2bf(v.w); a[7] = *(__bf16*)&r;
                    af[ks] = a;
                } else af[ks] = z;
            }
        } else {
            const v8bf* px = (const v8bf*)(X + (size_t)(ok ? arow : 0) * 128);
            #pragma unroll
            for (int ks = 0; ks < 4; ++ks) af[ks] = ok ? px[ks * 4 + quad] : z;
        }

        v4f acc[9];
        #pragma unroll
        for (int ct = 0; ct < 9; ++ct) acc[ct] = (v4f){0.f, 0.f, 0.f, 0.f};
        #pragma unroll
        for (int ct = 0; ct < 9; ++ct) {
            #pragma unroll
            for (int ks = 0; ks < 4; ++ks) {
                v8bf b = *(const v8bf*)&sWt[(ct * 16 + l16) * 136 + ks * 32 + quad * 8];
                acc[ct] = __builtin_amdgcn_mfma_f32_16x16x32_bf16(af[ks], b, acc[ct], 0, 0, 0);
            }
        }

        // h store (tiles 0..7): C layout col=l16, row=quad*4+reg
        #pragma unroll
        for (int reg = 0; reg < 4; ++reg) {
            int r = rowbase + quad * 4 + reg;
            if (r < n) {
                #pragma unroll
                for (int ct = 0; ct < 8; ++ct)
                    *(unsigned short*)&h[(size_t)r * 128 + ct * 16 + l16] = f2bf(acc[ct][reg]);
            }
        }
        // tile 8 = attention dots: cols l16: 0-3 s_hi, 4-7 s_lo, 8-11 d_hi, 12-15 d_lo
        #pragma unroll
        for (int reg = 0; reg < 4; ++reg) {
            float v = acc[8][reg] + __shfl_xor(acc[8][reg], 4);   // hi + lo
            int r = rowbase + quad * 4 + reg;
            if (r < n) {
                if (l16 < 4)                    a_s[r * 4 + l16] = v;
                else if (l16 >= 8 && l16 < 12)  a_d[r * 4 + (l16 - 8)] = v;
            }
        }
    }
}

// ---------------- GAT: 4 dst per wave (16 lanes each), 8-deep gather -------------
__global__ __launch_bounds__(256) void gat_aggr(
    const __hip_bfloat16* __restrict__ h, const float* __restrict__ a_s,
    const float* __restrict__ a_d,
    const int* __restrict__ rowptr, const int* __restrict__ colsrc,
    const float* __restrict__ bias, __hip_bfloat16* __restrict__ out, int n)
{
    __shared__ float s_w[4][4 * 16 * 4];           // [wave][q*64 + j*4 + head]
    int t = threadIdx.x;
    int wave = t >> 6, lane = t & 63;
    int q = lane >> 4, l16 = lane & 15;            // quarter = dst slot
    int d = blockIdx.x * 16 + wave * 4 + q;
    if (d >= n) d = n - 1;                         // duplicate work, benign
    int beg = rowptr[d];
    int cnt = rowptr[d + 1] - beg;
    int cm = max(cnt, __shfl_xor(cnt, 16));
    cm = max(cm, __shfl_xor(cm, 32));              // wave-uniform trip bound
    float4 ad4 = *(const float4*)&a_d[d * 4];
    float4 asd = *(const float4*)&a_s[d * 4];

    int ch = l16 * 8;                              // channels ch..ch+7
    int head = l16 >> 2;
    const char* hb = (const char*)h;
    unsigned chb = (unsigned)(ch << 1);            // byte offset within row
    int sbase = q * 64;                            // s_w base (floats)
    int lbase = q * 16;                            // shfl lane base

    float acc[8];
    #pragma unroll
    for (int i = 0; i < 8; ++i) acc[i] = 0.f;
    float zp = 0.f;                                // complete z for own head

    for (int j0 = 0; j0 < cm; j0 += 16) {
        int ne = cnt - j0;                         // own-dst remaining (may be <=0)
        float w0 = 0.f, w1 = 0.f, w2 = 0.f, w3 = 0.f;
        int s = 0;                                 // row 0 is a valid address
        if (l16 < ne) {
            s = colsrc[beg + j0 + l16];
            float4 sv = *(const float4*)&a_s[s * 4];
            w0 = __expf(lrelu(sv.x + ad4.x));
            w1 = __expf(lrelu(sv.y + ad4.y));
            w2 = __expf(lrelu(sv.z + ad4.z));
            w3 = __expf(lrelu(sv.w + ad4.w));
        }
        float4 wv = {w0, w1, w2, w3};              // zeros for pad lanes
        *(float4*)&s_w[wave][sbase + l16 * 4] = wv;
        __asm volatile("s_waitcnt lgkmcnt(0)" ::: "memory");  // wave-sync LDS
        // BRANCHLESS: s_w[j]==0 and s==0 for pad lanes / exhausted dsts.
        int nemax = cm - j0; if (nemax > 16) nemax = 16;
        int k = 0;
        for (; k + 8 <= nemax; k += 8) {           // 8 loads in flight per dst
            int   ss[8];
            float wj[8];
            int4  u[8];
            #pragma unroll
            for (int p2 = 0; p2 < 8; ++p2) {
                ss[p2] = __shfl(s, lbase + k + p2);
                wj[p2] = s_w[wave][sbase + (k + p2) * 4 + head];
            }
            #pragma unroll
            for (int p2 = 0; p2 < 8; ++p2)
                u[p2] = *(const int4*)(hb + (((unsigned)ss[p2] << 8) + chb));
            #pragma unroll
            for (int p2 = 0; p2 < 8; ++p2) { zp += wj[p2]; fma8(acc, u[p2], wj[p2]); }
        }
        for (; k + 4 <= nemax; k += 4) {           // 4-deep tail
            int ss0 = __shfl(s, lbase + k);
            int ss1 = __shfl(s, lbase + k + 1);
            int ss2 = __shfl(s, lbase + k + 2);
            int ss3 = __shfl(s, lbase + k + 3);
            float wj0 = s_w[wave][sbase + k * 4 + head];
            float wj1 = s_w[wave][sbase + (k + 1) * 4 + head];
            float wj2 = s_w[wave][sbase + (k + 2) * 4 + head];
            float wj3 = s_w[wave][sbase + (k + 3) * 4 + head];
            int4 u0 = *(const int4*)(hb + (((unsigned)ss0 << 8) + chb));
            int4 u1 = *(const int4*)(hb + (((unsigned)ss1 << 8) + chb));
            int4 u2 = *(const int4*)(hb + (((unsigned)ss2 << 8) + chb));
            int4 u3 = *(const int4*)(hb + (((unsigned)ss3 << 8) + chb));
            zp += (wj0 + wj1) + (wj2 + wj3);
            fma8(acc, u0, wj0);
            fma8(acc, u1, wj1);
            fma8(acc, u2, wj2);
            fma8(acc, u3, wj3);
        }
        for (; k < nemax; ++k) {                   // <=3 singles
            int ss0 = __shfl(s, lbase + k);
            float wj0 = s_w[wave][sbase + k * 4 + head];
            int4 u0 = *(const int4*)(hb + (((unsigned)ss0 << 8) + chb));
            zp += wj0;
            fma8(acc, u0, wj0);
        }
    }

    // epilogue: every lane writes 16B (16 lanes cover the 128-ch row)
    int4 hu = *(const int4*)(hb + (((unsigned)d << 8) + chb));
    float4 b0 = *(const float4*)&bias[ch];
    float4 b1 = *(const float4*)&bias[ch + 4];
    float eh0 = lrelu(asd.x + ad4.x), eh1 = lrelu(asd.y + ad4.y);
    float eh2 = lrelu(asd.z + ad4.z), eh3 = lrelu(asd.w + ad4.w);
    float eh = (head < 2) ? (head == 0 ? eh0 : eh1) : (head == 2 ? eh2 : eh3);
    float ws = __expf(eh);                         // self-loop weight
    float inv = 1.f / (zp + ws + 1e-16f);
    float hs[8] = {bflo(hu.x), bfhi(hu.x), bflo(hu.y), bfhi(hu.y),
                   bflo(hu.z), bfhi(hu.z), bflo(hu.w), bfhi(hu.w)};
    float o[8];
    o[0] = fmaxf((acc[0] + ws * hs[0]) * inv + b0.x, 0.f);
    o[1] = fmaxf((acc[1] + ws * hs[1]) * inv + b0.y, 0.f);
    o[2] = fmaxf((acc[2] + ws * hs[2]) * inv + b0.z, 0.f);
    o[3] = fmaxf((acc[3] + ws * hs[3]) * inv + b0.w, 0.f);
    o[4] = fmaxf((acc[4] + ws * hs[4]) * inv + b1.x, 0.f);
    o[5] = fmaxf((acc[5] + ws * hs[5]) * inv + b1.y, 0.f);
    o[6] = fmaxf((acc[6] + ws * hs[6]) * inv + b1.z, 0.f);
    o[7] = fmaxf((acc[7] + ws * hs[7]) * inv + b1.w, 0.f);
    int4 ou;
    ou.x = packbf2(o[0], o[1]); ou.y = packbf2(o[2], o[3]);
    ou.z = packbf2(o[4], o[5]); ou.w = packbf2(o[6], o[7]);
    *(int4*)&out[(size_t)d * 128 + ch] = ou;
}

// ---------------- GraphConv linear: y = x@Wr (bf16), root = x@Wl + b (fp32) -------
__global__ __launch_bounds__(256) void graphconv_lin(
    const __hip_bfloat16* __restrict__ Xb,
    const __hip_bfloat16* __restrict__ Wrt, const __hip_bfloat16* __restrict__ Wlt,
    const float* __restrict__ bias, __hip_bfloat16* __restrict__ y,
    float* __restrict__ root, int n)
{
    __shared__ __align__(16) __hip_bfloat16 sWr[32 * 136], sWl[32 * 136];
    int t = threadIdx.x;
    for (int i = t; i < 32 * 16; i += 256) {
        int row = i >> 4, chh = i & 15;
        *(int4*)&sWr[row * 136 + chh * 8] = *(const int4*)&Wrt[row * 128 + chh * 8];
        *(int4*)&sWl[row * 136 + chh * 8] = *(const int4*)&Wlt[row * 128 + chh * 8];
    }
    __syncthreads();
    int wave = t >> 6, lane = t & 63, quad = lane >> 4, l16 = lane & 15;

    v8bf z;
    #pragma unroll
    for (int i = 0; i < 8; ++i) z[i] = (__bf16)0.f;

    int nrb = (n + 15) >> 4;
    for (int rb = blockIdx.x * 4 + wave; rb < nrb; rb += gridDim.x * 4) {
        int rowbase = rb * 16;
        int arow = rowbase + l16;
        bool ok = arow < n;
        const v8bf* px = (const v8bf*)(Xb + (size_t)(ok ? arow : 0) * 128);
        v8bf fx[4];
        #pragma unroll
        for (int ks = 0; ks < 4; ++ks) fx[ks] = ok ? px[ks * 4 + quad] : z;

        v4f accR[2], accL[2];
        #pragma unroll
        for (int ct = 0; ct < 2; ++ct) {
            accR[ct] = (v4f){0.f, 0.f, 0.f, 0.f};
            accL[ct] = (v4f){0.f, 0.f, 0.f, 0.f};
            #pragma unroll
            for (int ks = 0; ks < 4; ++ks) {
                v8bf br = *(const v8bf*)&sWr[(ct * 16 + l16) * 136 + ks * 32 + quad * 8];
                accR[ct] = __builtin_amdgcn_mfma_f32_16x16x32_bf16(fx[ks], br, accR[ct], 0, 0, 0);
                v8bf bl = *(const v8bf*)&sWl[(ct * 16 + l16) * 136 + ks * 32 + quad * 8];
                accL[ct] = __builtin_amdgcn_mfma_f32_16x16x32_bf16(fx[ks], bl, accL[ct], 0, 0, 0);
            }
        }
        #pragma unroll
        for (int ct = 0; ct < 2; ++ct) {
            float bcol = bias[ct * 16 + l16];
            #pragma unroll
            for (int reg = 0; reg < 4; ++reg) {
                int r = rowbase + quad * 4 + reg;
                if (r < n) {
                    *(unsigned short*)&y[(size_t)r * 32 + ct * 16 + l16] = f2bf(accR[ct][reg]);
                    root[(size_t)r * 32 + ct * 16 + l16] = accL[ct][reg] + bcol;
                }
            }
        }
    }
}

// ---------------- GraphConv aggr: 8 dst per wave (8 lanes each), 32 ch -----------
__global__ __launch_bounds__(256) void graphconv_aggr(
    const __hip_bfloat16* __restrict__ y, const float* __restrict__ root,
    const int* __restrict__ rowptr, const int* __restrict__ colsrc,
    __hip_bfloat16* __restrict__ x3, int n)
{
    int t = threadIdx.x;
    int wave = t >> 6, lane = t & 63;
    int oct = lane >> 3, ol = lane & 7;            // octet = dst slot
    int d = blockIdx.x * 32 + wave * 8 + oct;
    if (d >= n) d = n - 1;
    int beg = rowptr[d];
    int cnt = rowptr[d + 1] - beg;
    int cm = max(cnt, __shfl_xor(cnt, 8));
    cm = max(cm, __shfl_xor(cm, 16));
    cm = max(cm, __shfl_xor(cm, 32));              // wave-uniform trip bound
    int l4 = ol & 3, egrp = ol >> 2;               // 2 edge-groups x 4 ch-lanes
    int ch = l4 * 8;
    int lbase = oct * 8;
    float acc[8];
    #pragma unroll
    for (int i = 0; i < 8; ++i) acc[i] = 0.f;
    for (int j0 = 0; j0 < cm; j0 += 8) {
        int ne = cnt - j0;                         // own-dst remaining
        int s = (ol < ne) ? colsrc[beg + j0 + ol] : 0;
        int nemax = cm - j0; if (nemax > 8) nemax = 8;
        int kmax = (nemax + 1) >> 1;               // uniform trip count
        int k = 0;
        for (; k + 2 <= kmax; k += 2) {            // 4 edges in flight
            int ja = egrp + 2 * k, jb = ja + 2;
            int sa = __shfl(s, lbase + ja);
            int sb = __shfl(s, lbase + jb);
            float ma = (ja < ne) ? 1.f : 0.f;      // branchless mask (own dst)
            float mb = (jb < ne) ? 1.f : 0.f;
            int4 ua = *(const int4*)&y[(size_t)sa * 32 + ch];
            int4 ub = *(const int4*)&y[(size_t)sb * 32 + ch];
            fma8(acc, ua, ma);
            fma8(acc, ub, mb);
        }
        if (k < kmax) {
            int ja = egrp + 2 * k;
            int sa = __shfl(s, lbase + ja);
            float ma = (ja < ne) ? 1.f : 0.f;
            int4 ua = *(const int4*)&y[(size_t)sa * 32 + ch];
            fma8(acc, ua, ma);
        }
    }
    float4 r0 = {0.f, 0.f, 0.f, 0.f}, r1 = {0.f, 0.f, 0.f, 0.f};
    if (egrp == 0) {                               // hoist above reduction
        r0 = *(const float4*)&root[(size_t)d * 32 + ch];
        r1 = *(const float4*)&root[(size_t)d * 32 + ch + 4];
    }
    #pragma unroll
    for (int i = 0; i < 8; ++i) acc[i] += __shfl_xor(acc[i], 4);   // combine 2 groups
    if (egrp == 0) {                               // 4 lanes per dst write 16B each
        float o[8];
        o[0] = fmaxf(acc[0] + r0.x, 0.f); o[1] = fmaxf(acc[1] + r0.y, 0.f);
        o[2] = fmaxf(acc[2] + r0.z, 0.f); o[3] = fmaxf(acc[3] + r0.w, 0.f);
        o[4] = fmaxf(acc[4] + r1.x, 0.f); o[5] = fmaxf(acc[5] + r1.y, 0.f);
        o[6] = fmaxf(acc[6] + r1.z, 0.f); o[7] = fmaxf(acc[7] + r1.w, 0.f);
        int4 ou;
        ou.x = packbf2(o[0], o[1]); ou.y = packbf2(o[2], o[3]);
        ou.z = packbf2(o[4], o[5]); ou.w = packbf2(o[6], o[7]);
        *(int4*)&x3[(size_t)d * 32 + ch] = ou;
    }
}

// ---------------- SAGE fused: mean-gather + 32x32 GEMM + global-mean-pool --------
// Block = 32 dsts (8 dst/wave gather). NO grid-wide fence (R15 lesson).
__global__ __launch_bounds__(256) void sage_fused(
    const __hip_bfloat16* __restrict__ x3, const int* __restrict__ rowptr,
    const int* __restrict__ colsrc,
    const float* __restrict__ Wl, const float* __restrict__ bl,
    const float* __restrict__ Wr,
    const int* __restrict__ batch, float* __restrict__ gpool, int n)
{
    __shared__ __align__(16) float sWl[32 * 32], sWr[32 * 32];
    __shared__ __align__(16) float smean[32 * 32], sx[32 * 32];
    __shared__ float sacc[64 * 32];                // per-graph pool partials
    __shared__ int sbat[32];
    int t = threadIdx.x;
    int row0 = blockIdx.x * 32;
    for (int i = t; i < 1024; i += 256) {
        sWl[i] = Wl[i]; sWr[i] = Wr[i];
    }
    for (int i = t; i < 2048; i += 256) sacc[i] = 0.f;
    if (t < 32) sbat[t] = batch[min(row0 + t, n - 1)];

    // ---- gather phase: 8 dst per wave, mean into LDS ----
    int wave = t >> 6, lane = t & 63;
    int oct = lane >> 3, ol = lane & 7;
    int slot = wave * 8 + oct;                     // 0..31
    int d = row0 + slot;
    if (d >= n) d = n - 1;
    int beg = rowptr[d];
    int cnt = rowptr[d + 1] - beg;
    int cm = max(cnt, __shfl_xor(cnt, 8));
    cm = max(cm, __shfl_xor(cm, 16));
    cm = max(cm, __shfl_xor(cm, 32));
    int l4 = ol & 3, egrp = ol >> 2;
    int ch = l4 * 8;
    int lbase = oct * 8;
    float acc[8];
    #pragma unroll
    for (int i = 0; i < 8; ++i) acc[i] = 0.f;
    for (int j0 = 0; j0 < cm; j0 += 8) {
        int ne = cnt - j0;
        int s = (ol < ne) ? colsrc[beg + j0 + ol] : 0;
        int nemax = cm - j0; if (nemax > 8) nemax = 8;
        int kmax = (nemax + 1) >> 1;
        int k = 0;
        for (; k + 2 <= kmax; k += 2) {
            int ja = egrp + 2 * k, jb = ja + 2;
            int sa = __shfl(s, lbase + ja);
            int sb = __shfl(s, lbase + jb);
            float ma = (ja < ne) ? 1.f : 0.f;
            float mb = (jb < ne) ? 1.f : 0.f;
            int4 ua = *(const int4*)&x3[(size_t)sa * 32 + ch];
            int4 ub = *(const int4*)&x3[(size_t)sb * 32 + ch];
            fma8(acc, ua, ma);
            fma8(acc, ub, mb);
        }
        if (k < kmax) {
            int ja = egrp + 2 * k;
            int sa = __shfl(s, lbase + ja);
            float ma = (ja < ne) ? 1.f : 0.f;
            int4 ua = *(const int4*)&x3[(size_t)sa * 32 + ch];
            fma8(acc, ua, ma);
        }
    }
    #pragma unroll
    for (int i = 0; i < 8; ++i) acc[i] += __shfl_xor(acc[i], 4);
    if (egrp == 0) {                               // stage mean + own x3 row
        float invd = 1.f / fmaxf((float)cnt, 1.f);
        float4 lo = {acc[0] * invd, acc[1] * invd, acc[2] * invd, acc[3] * invd};
        float4 hi = {acc[4] * invd, acc[5] * invd, acc[6] * invd, acc[7] * invd};
        *(float4*)&smean[slot * 32 + ch]     = lo;
        *(float4*)&smean[slot * 32 + ch + 4] = hi;
        int4 xu = *(const int4*)&x3[(size_t)d * 32 + ch];
        float4 x0 = {bflo(xu.x), bfhi(xu.x), bflo(xu.y), bfhi(xu.y)};
        float4 x1 = {bflo(xu.z), bfhi(xu.z), bflo(xu.w), bfhi(xu.w)};
        *(float4*)&sx[slot * 32 + ch]     = x0;
        *(float4*)&sx[slot * 32 + ch + 4] = x1;
    }
    __syncthreads();

    // ---- GEMM + pool-accumulate: thread (c = t&31) does rows rr, rr+8, ... ----
    int c = t & 31, rr = t >> 5;
    float bc = bl[c];
    int gbase = sbat[0];
    #pragma unroll
    for (int kr = 0; kr < 4; ++kr) {
        int r = rr + 8 * kr;
        float a = bc;
        const float4* pm = (const float4*)&smean[r * 32];
        const float4* px = (const float4*)&sx[r * 32];
        #pragma unroll
        for (int k4 = 0; k4 < 8; ++k4) {
            float4 vm = pm[k4], vx = px[k4];
            const float* wl = &sWl[(k4 * 4) * 32 + c];
            const float* wr = &sWr[(k4 * 4) * 32 + c];
            a += vm.x * wl[0] + vm.y * wl[32] + vm.z * wl[64] + vm.w * wl[96];
            a += vx.x * wr[0] + vx.y * wr[32] + vx.z * wr[64] + vx.w * wr[96];
        }
        float v = fmaxf(a, 0.f);
        int row = row0 + r;
        if (row < n) atomicAdd(&sacc[(sbat[r] - gbase) * 32 + c], v);
    }
    __syncthreads();
    int ngr = sbat[31] - gbase + 1;                // graphs spanned by this block
    for (int i = t; i < ngr * 32; i += 256) {
        float v = sacc[i];
        if (v != 0.f) atomicAdd(&gpool[(size_t)gbase * 32 + i], v);
    }
}

// ---------------- MLP head (divides pool sums by per-graph counts) ---------------
__device__ __forceinline__ int lower_bound_i(const int* a, int n, int key) {
    int lo = 0, hi = n;
    while (lo < hi) { int mid = (lo + hi) >> 1; if (a[mid] < key) lo = mid + 1; else hi = mid; }
    return lo;
}

__global__ __launch_bounds__(256) void head_kernel(
    const float* __restrict__ gpool, const int* __restrict__ batch, int n,
    const float* __restrict__ Wf1, const float* __restrict__ bf1,
    const float* __restrict__ Wf2, const float* __restrict__ bf2, float* __restrict__ out)
{
    __shared__ float sg[64 * 32], st[64 * 32];
    __shared__ float sW1[32 * 32], sW2[32 * 10];
    __shared__ float sinv[64];
    int t = threadIdx.x;
    if (t < 64) {
        int lo = lower_bound_i(batch, n, t);
        int hi = lower_bound_i(batch, n, t + 1);
        sinv[t] = 1.f / fmaxf((float)(hi - lo), 1.f);
    }
    for (int i = t; i < 1024; i += 256) sW1[i] = Wf1[i];
    for (int i = t; i < 320; i += 256) sW2[i] = Wf2[i];
    __syncthreads();
    for (int i = t; i < 2048; i += 256) sg[i] = gpool[i] * sinv[i >> 5];
    __syncthreads();
    for (int i = t; i < 2048; i += 256) {
        int g = i >> 5, c = i & 31;
        float acc = bf1[c];
        #pragma unroll
        for (int k = 0; k < 32; ++k) acc += sg[g * 32 + k] * sW1[k * 32 + c];
        st[i] = fmaxf(acc, 0.f);
    }
    __syncthreads();
    for (int i = t; i < 640; i += 256) {
        int g = i / 10, o = i - g * 10;
        float acc = bf2[o];
        #pragma unroll
        for (int k = 0; k < 32; ++k) acc += st[g * 32 + k] * sW2[k * 10 + o];
        out[i] = acc;
    }
}

extern "C" void kernel_launch(void* const* d_in, const int* in_sizes, int n_in,
                              void* d_out, int out_size, void* d_ws, size_t ws_size,
                              hipStream_t stream) {
    const float* x    = (const float*)d_in[0];
    const int*   ei   = (const int*)d_in[1];
    const int*   batch= (const int*)d_in[2];
    const float* W1   = (const float*)d_in[3];
    const float* as1  = (const float*)d_in[4];
    const float* ad1  = (const float*)d_in[5];
    const float* b1   = (const float*)d_in[6];
    const float* W2   = (const float*)d_in[7];
    const float* as2  = (const float*)d_in[8];
    const float* ad2  = (const float*)d_in[9];
    const float* b2   = (const float*)d_in[10];
    const float* W3r  = (const float*)d_in[11];
    const float* W3l  = (const float*)d_in[12];
    const float* b3   = (const float*)d_in[13];
    const float* W4l  = (const float*)d_in[14];
    const float* b4l  = (const float*)d_in[15];
    const float* W4r  = (const float*)d_in[16];
    const float* Wf1  = (const float*)d_in[17];
    const float* bf1  = (const float*)d_in[18];
    const float* Wf2  = (const float*)d_in[19];
    const float* bf2  = (const float*)d_in[20];

    const int N = in_sizes[0] / 128;
    const int E = in_sizes[1] / 2;
    const int* src = ei;
    const int* dst = ei + E;

    char* p = (char*)d_ws;
    auto alloc = [&](size_t bytes) -> void* {
        void* r = (void*)p;
        p += (bytes + 255) & ~(size_t)255;
        return r;
    };
    __hip_bfloat16* buf1 = (__hip_bfloat16*)alloc((size_t)N * 128 * 2);  // x2
    __hip_bfloat16* buf2 = (__hip_bfloat16*)alloc((size_t)N * 128 * 2);  // x1 / x3
    __hip_bfloat16* buf3 = (__hip_bfloat16*)alloc((size_t)N * 128 * 2);  // pairs / h1,h2 / y+root
    float* aS     = (float*)alloc((size_t)N * 4 * 4);
    float* aD     = (float*)alloc((size_t)N * 4 * 4);
    int*   rowptr = (int*)alloc((size_t)(N + 1) * 4);
    int*   colsrc = (int*)alloc((size_t)E * 4);
    int*   bcount = (int*)alloc(256 * 4);            // contiguous with gpool:
    float* gpool  = (float*)alloc(64 * 32 * 4);      // one memset covers both
    int*   bbase  = (int*)alloc(257 * 4);
    int*   gcursor= (int*)alloc(256 * 4);
    __hip_bfloat16* W1t  = (__hip_bfloat16*)alloc(144 * 128 * 2);
    __hip_bfloat16* W2t  = (__hip_bfloat16*)alloc(144 * 128 * 2);
    __hip_bfloat16* W3rt = (__hip_bfloat16*)alloc(32 * 128 * 2);
    __hip_bfloat16* W3lt = (__hip_bfloat16*)alloc(32 * 128 * 2);

    // aliased views
    __hip_bfloat16* X3b  = buf2;                                        // N*32 bf16
    __hip_bfloat16* Y32  = buf3;                                        // N*32 bf16
    float*          ROOT = (float*)((char*)buf3 + (((size_t)N * 32 * 2 + 255) & ~(size_t)255));
    int*            pairs = (int*)buf3;   // E*4 B, consumed before h is written

    const int nbuck = (N + 255) >> 8;     // 196 for N=50000 (requires N<=65536)

    // ---- bucketed CSR build + weight prep ----
    hipMemsetAsync(bcount, 0, 256 * 4 + 64 * 32 * 4, stream);   // bcount + gpool
    bucket_hist<<<(E + 4095) / 4096, 256, 0, stream>>>(dst, bcount, E, nbuck);
    scan_convert<<<65, 256, 0, stream>>>(bcount, bbase, gcursor, nbuck, E, rowptr, N,
                                         W1, W2, W3r, W3l, as1, ad1, as2, ad2,
                                         W1t, W2t, W3rt, W3lt);
    bucket_scatter<<<(E + 2047) / 2048, 256, 0, stream>>>(dst, src, gcursor, pairs, E, nbuck);
    bucket_fill<<<nbuck, 256, 0, stream>>>(pairs, bbase, rowptr, colsrc, N);

    int gmm = (N + 63) / 64;
    if (gmm > 320) gmm = 320;                      // grid-stride GEMMs
    const int gag4  = (N + 15) / 16;               // gat_aggr: 4 dst/wave
    const int gag8  = (N + 31) / 32;               // 32-ch aggr: 8 dst/wave
    // GAT layer 1 (reads fp32 x directly)
    gemm_att_mfma<float><<<gmm, 256, 0, stream>>>(x, W1t, buf3, aS, aD, N);
    gat_aggr<<<gag4, 256, 0, stream>>>(buf3, aS, aD, rowptr, colsrc, b1, buf2, N);
    // GAT layer 2
    gemm_att_mfma<__hip_bfloat16><<<gmm, 256, 0, stream>>>(buf2, W2t, buf3, aS, aD, N);
    gat_aggr<<<gag4, 256, 0, stream>>>(buf3, aS, aD, rowptr, colsrc, b2, buf1, N);
    // GraphConv (project first, then 64B-row gather)
    graphconv_lin<<<gmm, 256, 0, stream>>>(buf1, W3rt, W3lt, b3, Y32, ROOT, N);
    graphconv_aggr<<<gag8, 256, 0, stream>>>(Y32, ROOT, rowptr, colsrc, X3b, N);
    // SAGE + pool fused (mean gather -> 32x32 GEMM -> per-graph pool sums)
    sage_fused<<<gag8, 256, 0, stream>>>(X3b, rowptr, colsrc, W4l, b4l, W4r,
                                         batch, gpool, N);
    // head (divides pool sums by counts)
    head_kernel<<<1, 256, 0, stream>>>(gpool, batch, N, Wf1, bf1, Wf2, bf2, (float*)d_out);
}